// Round 4
// baseline (175.863 us; speedup 1.0000x reference)
//
#include <hip/hip_runtime.h>
#include <hip/hip_bf16.h>

typedef __attribute__((ext_vector_type(4))) float          fx4;
typedef __attribute__((ext_vector_type(8))) __bf16         bfx8;
typedef __attribute__((ext_vector_type(8))) unsigned short usx8;
typedef __attribute__((ext_vector_type(4))) unsigned short usx4;

#define TLEN 2048
#define ROWS 4096   /* B*T */
#define D    1024

__device__ __forceinline__ float bf2f(unsigned short u) {
    union { unsigned int i; float f; } v; v.i = ((unsigned int)u) << 16; return v.f;
}
__device__ __forceinline__ unsigned short f2bf(float f) {
    union { float f; unsigned int i; } v; v.f = f;
    unsigned int r = v.i + 0x7fffu + ((v.i >> 16) & 1u);
    return (unsigned short)(r >> 16);
}
__device__ __forceinline__ unsigned int cvtpk_bf16(float lo, float hi) {
    unsigned int r;
    asm("v_cvt_pk_bf16_f32 %0, %1, %2" : "=v"(r) : "v"(lo), "v"(hi));
    return r;
}
__device__ __forceinline__ void gload_lds16(const unsigned short* g, unsigned short* l) {
    __builtin_amdgcn_global_load_lds((const __attribute__((address_space(1))) void*)g,
                                     (__attribute__((address_space(3))) void*)l, 16, 0, 0);
}

// ---------------- LayerNorm: fp32 x -> bf16 h ----------------
__global__ __launch_bounds__(256) void ln_kernel(const float* __restrict__ x,
                                                 const float* __restrict__ g,
                                                 const float* __restrict__ bta,
                                                 unsigned short* __restrict__ hout) {
    const int row = blockIdx.x, tid = threadIdx.x;
    fx4 v = ((const fx4*)(x + (size_t)row * D))[tid];
    float s  = v[0] + v[1] + v[2] + v[3];
    float s2 = v[0]*v[0] + v[1]*v[1] + v[2]*v[2] + v[3]*v[3];
    #pragma unroll
    for (int mk = 32; mk >= 1; mk >>= 1) { s += __shfl_xor(s, mk); s2 += __shfl_xor(s2, mk); }
    __shared__ float red[8];
    const int wave = tid >> 6, lane = tid & 63;
    if (lane == 0) { red[wave] = s; red[4 + wave] = s2; }
    __syncthreads();
    s  = red[0] + red[1] + red[2] + red[3];
    s2 = red[4] + red[5] + red[6] + red[7];
    float mu   = s * (1.0f / D);
    float var  = s2 * (1.0f / D) - mu * mu;
    float rstd = rsqrtf(var + 1e-5f);
    fx4 gv = ((const fx4*)g)[tid];
    fx4 bv = ((const fx4*)bta)[tid];
    usx4 o;
    #pragma unroll
    for (int j = 0; j < 4; j++) o[j] = f2bf((v[j] - mu) * rstd * gv[j] + bv[j]);
    ((usx4*)hout)[(size_t)row * 256 + tid] = o;
}

// ---------------- Weight convert: fp32 -> bf16, wq|wk|wv concat ----------------
__device__ __forceinline__ usx4 cvt4(fx4 a) {
    usx4 o;
    #pragma unroll
    for (int j = 0; j < 4; j++) o[j] = f2bf(a[j]);
    return o;
}
__global__ __launch_bounds__(256) void wconv_kernel(const float* __restrict__ wq, const float* __restrict__ wk,
                                                    const float* __restrict__ wv, const float* __restrict__ wo,
                                                    unsigned short* __restrict__ wqkv,
                                                    unsigned short* __restrict__ wob) {
    const int i = blockIdx.x * 256 + threadIdx.x;   // usx4 units, 262144 per matrix
    ((usx4*)wqkv)[i]          = cvt4(((const fx4*)wq)[i]);
    ((usx4*)wqkv)[262144 + i] = cvt4(((const fx4*)wk)[i]);
    ((usx4*)wqkv)[524288 + i] = cvt4(((const fx4*)wv)[i]);
    ((usx4*)wob)[i]           = cvt4(((const fx4*)wo)[i]);
}

// ---------------- GEMM C[M,N] = A[M,K] * B[N,K]^T ----------------
// m97 structure: 128x128 tile, BK=32, 4 waves (2x2), global_load_lds width 16.
// MODE 1: f32 out (ldc).  MODE 2: QKV split — q,k bf16 -> Cqk [row][2048];
// v -> Vt[b][h][d][t] (pre-transposed for attention's V^T staging).
template<int MODE>
__global__ __launch_bounds__(256) void gemm_bt(const unsigned short* __restrict__ A,
                                               const unsigned short* __restrict__ B,
                                               void* __restrict__ C,
                                               unsigned short* __restrict__ Vt, int ldc) {
    constexpr int K = 1024;
    __shared__ __align__(16) unsigned short As[128 * 32];
    __shared__ __align__(16) unsigned short Bs[128 * 32];
    const int tid = threadIdx.x, lane = tid & 63, wave = tid >> 6;
    const int fr = lane & 15, fq = lane >> 4;
    const int bm = blockIdx.x, bn = blockIdx.y;
    const int wr = wave >> 1, wc = wave & 1;

    const int str0 = wave * 32 + (lane >> 2);
    const int stc  = (lane & 3) * 8;
    const unsigned short* Ab = A + (size_t)(bm * 128) * K;
    const unsigned short* Bb = B + (size_t)(bn * 128) * K;

    fx4 acc[4][4];
    #pragma unroll
    for (int m = 0; m < 4; m++)
        #pragma unroll
        for (int n = 0; n < 4; n++) acc[m][n] = (fx4)0.0f;

    for (int kt = 0; kt < K; kt += 32) {
        gload_lds16(Ab + (size_t)str0 * K + kt + stc,        &As[str0 * 32 + stc]);
        gload_lds16(Ab + (size_t)(str0 + 16) * K + kt + stc, &As[(str0 + 16) * 32 + stc]);
        gload_lds16(Bb + (size_t)str0 * K + kt + stc,        &Bs[str0 * 32 + stc]);
        gload_lds16(Bb + (size_t)(str0 + 16) * K + kt + stc, &Bs[(str0 + 16) * 32 + stc]);
        __syncthreads();
        bfx8 aF[4], bF[4];
        #pragma unroll
        for (int m = 0; m < 4; m++) aF[m] = *(const bfx8*)&As[(wr * 64 + m * 16 + fr) * 32 + fq * 8];
        #pragma unroll
        for (int n = 0; n < 4; n++) bF[n] = *(const bfx8*)&Bs[(wc * 64 + n * 16 + fr) * 32 + fq * 8];
        #pragma unroll
        for (int m = 0; m < 4; m++)
            #pragma unroll
            for (int n = 0; n < 4; n++)
                acc[m][n] = __builtin_amdgcn_mfma_f32_16x16x32_bf16(aF[m], bF[n], acc[m][n], 0, 0, 0);
        __syncthreads();
    }

    if (MODE == 1) {
        const int row0 = bm * 128 + wr * 64 + fq * 4;
        const int col0 = bn * 128 + wc * 64 + fr;
        #pragma unroll
        for (int m = 0; m < 4; m++)
            #pragma unroll
            for (int n = 0; n < 4; n++)
                #pragma unroll
                for (int j = 0; j < 4; j++)
                    ((float*)C)[(size_t)(row0 + m * 16 + j) * ldc + col0 + n * 16] = acc[m][n][j];
    } else if (bn < 16) {
        // q,k region: bf16, row stride 2048
        const int row0 = bm * 128 + wr * 64 + fq * 4;
        const int col0 = bn * 128 + wc * 64 + fr;
        #pragma unroll
        for (int m = 0; m < 4; m++)
            #pragma unroll
            for (int n = 0; n < 4; n++)
                #pragma unroll
                for (int j = 0; j < 4; j++)
                    ((unsigned short*)C)[(size_t)(row0 + m * 16 + j) * 2048 + col0 + n * 16] = f2bf(acc[m][n][j]);
    } else {
        // v region: transposed store Vt[(b*16+h)*64 + d][t], 4 consecutive t per lane -> b64
        const int bb = bm >> 4;                               // batch (block never straddles)
        const int tbase = (bm & 15) * 128 + wr * 64 + fq * 4; // token base within batch
        #pragma unroll
        for (int m = 0; m < 4; m++)
            #pragma unroll
            for (int n = 0; n < 4; n++) {
                int dg = (bn - 16) * 128 + wc * 64 + n * 16 + fr;   // 0..1023
                int h = dg >> 6, d = dg & 63;
                usx4 o4;
                #pragma unroll
                for (int j = 0; j < 4; j++) o4[j] = f2bf(acc[m][n][j]);
                *(usx4*)&Vt[(((size_t)(bb * 16 + h) * 64 + d) << 11) + tbase + m * 16] = o4;
            }
    }
}

// ---------------- RoPE in-place on q,k (q also pre-scaled by 0.125*log2e) ----------------
__global__ __launch_bounds__(256) void rope_kernel(unsigned short* __restrict__ qk,
                                                   const float* __restrict__ cosT,
                                                   const float* __restrict__ sinT) {
    int idx = blockIdx.x * 256 + threadIdx.x;   // 4096 rows * 512 pairs
    int row = idx >> 9;
    int p   = idx & 511;
    int head = p >> 5, pi = p & 31;
    int t = row & (TLEN - 1);
    float c = cosT[t * 32 + pi], s = sinT[t * 32 + pi];
    size_t qoff = (size_t)row * 2048 + head * 64 + pi * 2;
    const float QS = 0.125f * 1.44269504088896f;   // scale * log2(e): softmax via exp2
    unsigned int uq = *(const unsigned int*)&qk[qoff];
    float x0 = bf2f((unsigned short)(uq & 0xffff));
    float x1 = bf2f((unsigned short)(uq >> 16));
    unsigned int r0 = f2bf((x0 * c - x1 * s) * QS);
    unsigned int r1 = f2bf((x0 * s + x1 * c) * QS);
    *(unsigned int*)&qk[qoff] = r0 | (r1 << 16);
    size_t koff = qoff + 1024;
    unsigned int uk = *(const unsigned int*)&qk[koff];
    x0 = bf2f((unsigned short)(uk & 0xffff));
    x1 = bf2f((unsigned short)(uk >> 16));
    r0 = f2bf(x0 * c - x1 * s);
    r1 = f2bf(x0 * s + x1 * c);
    *(unsigned int*)&qk[koff] = r0 | (r1 << 16);
}

// ---------------- Flash attention (full, non-causal), bf16 MFMA ----------------
// 4 waves; wave owns 16 q-rows; KVBLK=64. Swapped QK^T (lane-local softmax),
// in-register P butterfly, swapped PV. K and pre-transposed V^T both staged via
// global_load_lds with both-sides XOR swizzle; double-buffered; defer-max.
__global__ __launch_bounds__(256) void attn_kernel(const unsigned short* __restrict__ qk,
                                                   const unsigned short* __restrict__ vt,
                                                   unsigned short* __restrict__ ao) {
    // XCD swizzle: 1024 blocks -> each XCD hosts 4 consecutive bh groups
    const int flat = blockIdx.x + (blockIdx.y << 5);
    const int sid  = (flat & 7) * 128 + (flat >> 3);
    const int qt = sid & 31, bh = sid >> 5;
    const int b = bh >> 4, hh = bh & 15;
    const int tid = threadIdx.x, lane = tid & 63, wave = tid >> 6;
    const int fr = lane & 15, fq = lane >> 4;

    __shared__ __align__(16) unsigned short sK[2][64 * 64];   // swizzled K tile
    __shared__ __align__(16) unsigned short sVt[2][64 * 64];  // swizzled V^T tile

    const size_t rs = 2048;
    const unsigned short* qb  = qk + (size_t)b * TLEN * rs + hh * 64;
    const unsigned short* kb  = qb + 1024;
    const unsigned short* vtb = vt + (size_t)bh * (64 * 2048);

    bfx8 qF[2];
    {
        int qrow = qt * 64 + wave * 16 + fr;
        const unsigned short* qp = qb + (size_t)qrow * rs + fq * 8;
        qF[0] = *(const bfx8*)qp;
        qF[1] = *(const bfx8*)(qp + 32);
    }

    // staging geometry: wave stages row-groups rg=wave*2+{0,1} (8 rows each);
    // LDS dest linear (lane*16B), global source col pre-swizzled (both-sides XOR).
    const int srow = lane >> 3;
    const int scol = ((lane & 7) ^ srow) * 8;

    // ---- prologue: stage tile 0 into buf 0
    #pragma unroll
    for (int i = 0; i < 2; i++) {
        int rg = wave * 2 + i;
        gload_lds16(kb  + (size_t)(rg * 8 + srow) * rs + scol,   &sK[0][rg * 512 + lane * 8]);
        gload_lds16(vtb + (size_t)(rg * 8 + srow) * 2048 + scol, &sVt[0][rg * 512 + lane * 8]);
    }

    float m_run = -1e30f, l_run = 0.0f;
    fx4 oacc[4];
    #pragma unroll
    for (int db = 0; db < 4; db++) oacc[db] = (fx4)0.0f;

    const int f1 = (lane >> 5) & 1, f0 = (lane >> 4) & 1;

    for (int t = 0; t < 32; ++t) {
        const int buf = t & 1;
        __syncthreads();   // staging of buf drained; prior reads of buf^1 done

        // ---- prefetch next tile into buf^1 (async, drains at next barrier)
        if (t + 1 < 32) {
            const int kt = (t + 1) * 64;
            #pragma unroll
            for (int i = 0; i < 2; i++) {
                int rg = wave * 2 + i;
                gload_lds16(kb  + (size_t)(kt + rg * 8 + srow) * rs + scol,
                            &sK[buf ^ 1][rg * 512 + lane * 8]);
                gload_lds16(vtb + (size_t)(rg * 8 + srow) * 2048 + kt + scol,
                            &sVt[buf ^ 1][rg * 512 + lane * 8]);
            }
        }

        // ---- QK^T swapped: sacc[n] holds S[kv = n*16+fq*4+j][q = fr]
        fx4 sacc[4];
        #pragma unroll
        for (int n = 0; n < 4; n++) sacc[n] = (fx4)0.0f;
        #pragma unroll
        for (int s = 0; s < 2; s++)
            #pragma unroll
            for (int n = 0; n < 4; n++) {
                bfx8 kF = *(const bfx8*)&sK[buf][(n * 16 + fr) * 64 + (((s * 4 + fq) ^ (fr & 7)) * 8)];
                sacc[n] = __builtin_amdgcn_mfma_f32_16x16x32_bf16(kF, qF[s], sacc[n], 0, 0, 0);
            }

        // ---- online softmax, lane-local for q=fr (reduce over fq: masks 16,32)
        float t0 = fmaxf(fmaxf(sacc[0][0], sacc[0][1]), sacc[0][2]);
        float t1 = fmaxf(fmaxf(sacc[0][3], sacc[1][0]), sacc[1][1]);
        float t2 = fmaxf(fmaxf(sacc[1][2], sacc[1][3]), sacc[2][0]);
        float t3 = fmaxf(fmaxf(sacc[2][1], sacc[2][2]), sacc[2][3]);
        float t4 = fmaxf(fmaxf(sacc[3][0], sacc[3][1]), sacc[3][2]);
        float smax = fmaxf(fmaxf(fmaxf(t0, t1), t2), fmaxf(fmaxf(t3, t4), sacc[3][3]));
        smax = fmaxf(smax, __shfl_xor(smax, 16));
        smax = fmaxf(smax, __shfl_xor(smax, 32));
        if (!__all(smax <= m_run + 8.0f)) {        // defer-max: P bounded by 2^8
            float mnew = fmaxf(m_run, smax);
            float scal = exp2f(m_run - mnew);
            l_run *= scal;
            #pragma unroll
            for (int db = 0; db < 4; db++) oacc[db] *= scal;
            m_run = mnew;
        }
        float p[4][4];
        float ps = 0.0f;
        #pragma unroll
        for (int n = 0; n < 4; n++)
            #pragma unroll
            for (int j = 0; j < 4; j++) { p[n][j] = exp2f(sacc[n][j] - m_run); ps += p[n][j]; }
        ps += __shfl_xor(ps, 16);
        ps += __shfl_xor(ps, 32);
        l_run += ps;

        // ---- pack P to bf16 pairs (v_cvt_pk), butterfly into PV B-operand layout
        unsigned int u[4][2];
        #pragma unroll
        for (int n = 0; n < 4; n++)
            #pragma unroll
            for (int h = 0; h < 2; h++)
                u[n][h] = cvtpk_bf16(p[n][2 * h], p[n][2 * h + 1]);
        unsigned int y[2][2], rA[2][2];
        #pragma unroll
        for (int m = 0; m < 2; m++)
            #pragma unroll
            for (int h = 0; h < 2; h++) {
                y[m][h] = f1 ? u[2 * m + 1][h] : u[2 * m][h];
                unsigned int x = f1 ? u[2 * m][h] : u[2 * m + 1][h];
                rA[m][h] = __shfl_xor((int)x, 32);
            }
        unsigned int w[2][4];
        #pragma unroll
        for (int m = 0; m < 2; m++)
            #pragma unroll
            for (int h = 0; h < 2; h++) {
                unsigned int kp = (f1 == f0) ? y[m][h] : rA[m][h];
                unsigned int z  = (f1 != f0) ? y[m][h] : rA[m][h];
                unsigned int rc = __shfl_xor((int)z, 16);
                w[m][h]     = f0 ? rc : kp;
                w[m][2 + h] = f0 ? kp : rc;
            }

        // ---- PV swapped: oacc[db] = O^T[d = db*16+fq*4+j][q = fr]
        #pragma unroll
        for (int s = 0; s < 2; s++) {
            union { unsigned int ui[4]; bfx8 bf; } cv;
            cv.ui[0] = w[s][0]; cv.ui[1] = w[s][1]; cv.ui[2] = w[s][2]; cv.ui[3] = w[s][3];
            #pragma unroll
            for (int db = 0; db < 4; db++) {
                bfx8 vF = *(const bfx8*)&sVt[buf][(db * 16 + fr) * 64 + (((s * 4 + fq) ^ (fr & 7)) * 8)];
                oacc[db] = __builtin_amdgcn_mfma_f32_16x16x32_bf16(vF, cv.bf, oacc[db], 0, 0, 0);
            }
        }
    }

    // ---- epilogue: O^T in regs -> ao row-major
    float invl = 1.0f / l_run;
    const int qrow = qt * 64 + wave * 16 + fr;
    unsigned short* aop = ao + (size_t)(b * TLEN + qrow) * 1024 + hh * 64 + fq * 4;
    #pragma unroll
    for (int db = 0; db < 4; db++) {
        usx4 o4;
        #pragma unroll
        for (int j = 0; j < 4; j++) o4[j] = f2bf(oacc[db][j] * invl);
        *(usx4*)(aop + db * 16) = o4;
    }
}

extern "C" void kernel_launch(void* const* d_in, const int* in_sizes, int n_in,
                              void* d_out, int out_size, void* d_ws, size_t ws_size,
                              hipStream_t stream) {
    const float* x    = (const float*)d_in[0];
    const float* wq   = (const float*)d_in[1];
    const float* wk   = (const float*)d_in[2];
    const float* wv   = (const float*)d_in[3];
    const float* wo   = (const float*)d_in[4];
    const float* lng  = (const float*)d_in[5];
    const float* lnb  = (const float*)d_in[6];
    const float* cosT = (const float*)d_in[7];
    const float* sinT = (const float*)d_in[8];

    char* ws = (char*)d_ws;
    unsigned short* wob  = (unsigned short*)(ws);                // 2 MB  [1024][1024] bf16
    unsigned short* wqkv = (unsigned short*)(ws + (2u  << 20));  // 6 MB  [3072][1024] bf16
    unsigned short* hbuf = (unsigned short*)(ws + (8u  << 20));  // 8 MB  [4096][1024] bf16
    unsigned short* qk   = (unsigned short*)(ws + (16u << 20));  // 16 MB [4096][2048] bf16 (q|k)
    unsigned short* vtb  = (unsigned short*)(ws + (32u << 20));  // 8 MB  [32 bh][64 d][2048 t]
    unsigned short* ao   = (unsigned short*)(ws + (8u  << 20));  // aliases hbuf (dead after QKV GEMM)

    ln_kernel<<<ROWS, 256, 0, stream>>>(x, lng, lnb, hbuf);
    wconv_kernel<<<1024, 256, 0, stream>>>(wq, wk, wv, wo, wqkv, wob);
    gemm_bt<2><<<dim3(32, 24), 256, 0, stream>>>(hbuf, wqkv, qk, vtb, 2048);
    rope_kernel<<<8192, 256, 0, stream>>>(qk, cosT, sinT);
    attn_kernel<<<dim3(32, 32), 256, 0, stream>>>(qk, vtb, ao);
    gemm_bt<1><<<dim3(32, 8), 256, 0, stream>>>(ao, wob, (float*)d_out, nullptr, 1024);
}

// Round 6
// 158.601 us; speedup vs baseline: 1.1088x; 1.1088x over previous
//
#include <hip/hip_runtime.h>
#include <hip/hip_bf16.h>

typedef __attribute__((ext_vector_type(4))) float          fx4;
typedef __attribute__((ext_vector_type(8))) __bf16         bfx8;
typedef __attribute__((ext_vector_type(8))) unsigned short usx8;
typedef __attribute__((ext_vector_type(4))) unsigned short usx4;

#define TLEN 2048
#define ROWS 4096   /* B*T */
#define D    1024

__device__ __forceinline__ float bf2f(unsigned short u) {
    union { unsigned int i; float f; } v; v.i = ((unsigned int)u) << 16; return v.f;
}
__device__ __forceinline__ unsigned short f2bf(float f) {
    union { float f; unsigned int i; } v; v.f = f;
    unsigned int r = v.i + 0x7fffu + ((v.i >> 16) & 1u);
    return (unsigned short)(r >> 16);
}
__device__ __forceinline__ unsigned int cvtpk_bf16(float lo, float hi) {
    unsigned int r;
    asm("v_cvt_pk_bf16_f32 %0, %1, %2" : "=v"(r) : "v"(lo), "v"(hi));
    return r;
}
__device__ __forceinline__ void gload_lds16(const unsigned short* g, unsigned short* l) {
    __builtin_amdgcn_global_load_lds((const __attribute__((address_space(1))) void*)g,
                                     (__attribute__((address_space(3))) void*)l, 16, 0, 0);
}

// ---------------- LayerNorm: fp32 x -> bf16 h ----------------
__global__ __launch_bounds__(256) void ln_kernel(const float* __restrict__ x,
                                                 const float* __restrict__ g,
                                                 const float* __restrict__ bta,
                                                 unsigned short* __restrict__ hout) {
    const int row = blockIdx.x, tid = threadIdx.x;
    fx4 v = ((const fx4*)(x + (size_t)row * D))[tid];
    float s  = v[0] + v[1] + v[2] + v[3];
    float s2 = v[0]*v[0] + v[1]*v[1] + v[2]*v[2] + v[3]*v[3];
    #pragma unroll
    for (int mk = 32; mk >= 1; mk >>= 1) { s += __shfl_xor(s, mk); s2 += __shfl_xor(s2, mk); }
    __shared__ float red[8];
    const int wave = tid >> 6, lane = tid & 63;
    if (lane == 0) { red[wave] = s; red[4 + wave] = s2; }
    __syncthreads();
    s  = red[0] + red[1] + red[2] + red[3];
    s2 = red[4] + red[5] + red[6] + red[7];
    float mu   = s * (1.0f / D);
    float var  = s2 * (1.0f / D) - mu * mu;
    float rstd = rsqrtf(var + 1e-5f);
    fx4 gv = ((const fx4*)g)[tid];
    fx4 bv = ((const fx4*)bta)[tid];
    usx4 o;
    #pragma unroll
    for (int j = 0; j < 4; j++) o[j] = f2bf((v[j] - mu) * rstd * gv[j] + bv[j]);
    ((usx4*)hout)[(size_t)row * 256 + tid] = o;
}

// ---------------- Weight convert: fp32 -> bf16, wq|wk|wv concat ----------------
__device__ __forceinline__ usx4 cvt4(fx4 a) {
    usx4 o;
    #pragma unroll
    for (int j = 0; j < 4; j++) o[j] = f2bf(a[j]);
    return o;
}
__global__ __launch_bounds__(256) void wconv_kernel(const float* __restrict__ wq, const float* __restrict__ wk,
                                                    const float* __restrict__ wv, const float* __restrict__ wo,
                                                    unsigned short* __restrict__ wqkv,
                                                    unsigned short* __restrict__ wob) {
    const int i = blockIdx.x * 256 + threadIdx.x;   // usx4 units, 262144 per matrix
    ((usx4*)wqkv)[i]          = cvt4(((const fx4*)wq)[i]);
    ((usx4*)wqkv)[262144 + i] = cvt4(((const fx4*)wk)[i]);
    ((usx4*)wqkv)[524288 + i] = cvt4(((const fx4*)wv)[i]);
    ((usx4*)wob)[i]           = cvt4(((const fx4*)wo)[i]);
}

// ---------------- GEMM C[M,N] = A[M,K] * B[N,K]^T ----------------
// m97 structure: 128x128 tile, BK=32, 4 waves (2x2), global_load_lds width 16.
// MODE 0: bf16 out, row stride ldc.  MODE 1: f32 out, row stride ldc.
// MODE 2: Vt-mapped bf16 out — rows are d (0..1023), cols are tokens;
//         store to Vt[(b*16 + d>>6)*64 + (d&63)][t] (coalesced along t).
template<int MODE>
__global__ __launch_bounds__(256) void gemm_bt(const unsigned short* __restrict__ A,
                                               const unsigned short* __restrict__ B,
                                               void* __restrict__ C, int ldc) {
    constexpr int K = 1024;
    __shared__ __align__(16) unsigned short As[128 * 32];
    __shared__ __align__(16) unsigned short Bs[128 * 32];
    const int tid = threadIdx.x, lane = tid & 63, wave = tid >> 6;
    const int fr = lane & 15, fq = lane >> 4;
    const int bm = blockIdx.x, bn = blockIdx.y;
    const int wr = wave >> 1, wc = wave & 1;

    const int str0 = wave * 32 + (lane >> 2);
    const int stc  = (lane & 3) * 8;
    const unsigned short* Ab = A + (size_t)(bm * 128) * K;
    const unsigned short* Bb = B + (size_t)(bn * 128) * K;

    fx4 acc[4][4];
    #pragma unroll
    for (int m = 0; m < 4; m++)
        #pragma unroll
        for (int n = 0; n < 4; n++) acc[m][n] = (fx4)0.0f;

    for (int kt = 0; kt < K; kt += 32) {
        gload_lds16(Ab + (size_t)str0 * K + kt + stc,        &As[str0 * 32 + stc]);
        gload_lds16(Ab + (size_t)(str0 + 16) * K + kt + stc, &As[(str0 + 16) * 32 + stc]);
        gload_lds16(Bb + (size_t)str0 * K + kt + stc,        &Bs[str0 * 32 + stc]);
        gload_lds16(Bb + (size_t)(str0 + 16) * K + kt + stc, &Bs[(str0 + 16) * 32 + stc]);
        __syncthreads();
        bfx8 aF[4], bF[4];
        #pragma unroll
        for (int m = 0; m < 4; m++) aF[m] = *(const bfx8*)&As[(wr * 64 + m * 16 + fr) * 32 + fq * 8];
        #pragma unroll
        for (int n = 0; n < 4; n++) bF[n] = *(const bfx8*)&Bs[(wc * 64 + n * 16 + fr) * 32 + fq * 8];
        #pragma unroll
        for (int m = 0; m < 4; m++)
            #pragma unroll
            for (int n = 0; n < 4; n++)
                acc[m][n] = __builtin_amdgcn_mfma_f32_16x16x32_bf16(aF[m], bF[n], acc[m][n], 0, 0, 0);
        __syncthreads();
    }

    const int row0 = bm * 128 + wr * 64 + fq * 4;
    const int col0 = bn * 128 + wc * 64 + fr;
    if (MODE == 0) {
        #pragma unroll
        for (int m = 0; m < 4; m++)
            #pragma unroll
            for (int n = 0; n < 4; n++)
                #pragma unroll
                for (int j = 0; j < 4; j++)
                    ((unsigned short*)C)[(size_t)(row0 + m * 16 + j) * ldc + col0 + n * 16] = f2bf(acc[m][n][j]);
    } else if (MODE == 1) {
        #pragma unroll
        for (int m = 0; m < 4; m++)
            #pragma unroll
            for (int n = 0; n < 4; n++)
                #pragma unroll
                for (int j = 0; j < 4; j++)
                    ((float*)C)[(size_t)(row0 + m * 16 + j) * ldc + col0 + n * 16] = acc[m][n][j];
    } else {
        // Vt: rows=d, cols=token. b = bn>>4 (128-wide block never straddles batch).
        unsigned short* Vt = (unsigned short*)C;
        const int bb = bn >> 4;
        #pragma unroll
        for (int m = 0; m < 4; m++)
            #pragma unroll
            for (int n = 0; n < 4; n++) {
                const int t = (col0 + n * 16) & (TLEN - 1);
                #pragma unroll
                for (int j = 0; j < 4; j++) {
                    const int d = row0 + m * 16 + j;
                    Vt[(((size_t)(bb * 16 + (d >> 6)) * 64) + (d & 63)) * TLEN + t] = f2bf(acc[m][n][j]);
                }
            }
    }
}

// ---------------- RoPE in-place on q,k (q also pre-scaled by 0.125*log2e) ----------------
__global__ __launch_bounds__(256) void rope_kernel(unsigned short* __restrict__ qk,
                                                   const float* __restrict__ cosT,
                                                   const float* __restrict__ sinT) {
    int idx = blockIdx.x * 256 + threadIdx.x;   // 4096 rows * 512 pairs
    int row = idx >> 9;
    int p   = idx & 511;
    int head = p >> 5, pi = p & 31;
    int t = row & (TLEN - 1);
    float c = cosT[t * 32 + pi], s = sinT[t * 32 + pi];
    size_t qoff = (size_t)row * 2048 + head * 64 + pi * 2;
    const float QS = 0.125f * 1.44269504088896f;   // scale * log2(e): softmax via exp2
    unsigned int uq = *(const unsigned int*)&qk[qoff];
    float x0 = bf2f((unsigned short)(uq & 0xffff));
    float x1 = bf2f((unsigned short)(uq >> 16));
    unsigned int r0 = f2bf((x0 * c - x1 * s) * QS);
    unsigned int r1 = f2bf((x0 * s + x1 * c) * QS);
    *(unsigned int*)&qk[qoff] = r0 | (r1 << 16);
    size_t koff = qoff + 1024;
    unsigned int uk = *(const unsigned int*)&qk[koff];
    x0 = bf2f((unsigned short)(uk & 0xffff));
    x1 = bf2f((unsigned short)(uk >> 16));
    r0 = f2bf(x0 * c - x1 * s);
    r1 = f2bf(x0 * s + x1 * c);
    *(unsigned int*)&qk[koff] = r0 | (r1 << 16);
}

// ---------------- Flash attention (full, non-causal), bf16 MFMA ----------------
// 4 waves; wave owns 16 q-rows; KVBLK=64. Swapped QK^T (lane-local softmax),
// in-register P via permlane32_swap butterfly, swapped PV. K and pre-transposed
// V^T staged via global_load_lds with both-sides XOR swizzle; double-buffered.
__global__ __launch_bounds__(256) void attn_kernel(const unsigned short* __restrict__ qk,
                                                   const unsigned short* __restrict__ vt,
                                                   unsigned short* __restrict__ ao) {
    // XCD swizzle: 1024 blocks -> each XCD hosts 4 consecutive bh groups
    const int flat = blockIdx.x + (blockIdx.y << 5);
    const int sid  = (flat & 7) * 128 + (flat >> 3);
    const int qt = sid & 31, bh = sid >> 5;
    const int b = bh >> 4, hh = bh & 15;
    const int tid = threadIdx.x, lane = tid & 63, wave = tid >> 6;
    const int fr = lane & 15, fq = lane >> 4;

    __shared__ __align__(16) unsigned short sK[2][64 * 64];   // swizzled K tile
    __shared__ __align__(16) unsigned short sVt[2][64 * 64];  // swizzled V^T tile

    const size_t rs = 2048;
    const unsigned short* qb  = qk + (size_t)b * TLEN * rs + hh * 64;
    const unsigned short* kb  = qb + 1024;
    const unsigned short* vtb = vt + (size_t)bh * (64 * TLEN);

    bfx8 qF[2];
    {
        int qrow = qt * 64 + wave * 16 + fr;
        const unsigned short* qp = qb + (size_t)qrow * rs + fq * 8;
        qF[0] = *(const bfx8*)qp;
        qF[1] = *(const bfx8*)(qp + 32);
    }

    // staging geometry: wave stages row-groups rg=wave*2+{0,1} (8 rows each);
    // LDS dest linear (lane*16B), global source col pre-swizzled (both-sides XOR).
    const int srow = lane >> 3;
    const int scol = ((lane & 7) ^ srow) * 8;

    // ---- prologue: stage tile 0 into buf 0
    #pragma unroll
    for (int i = 0; i < 2; i++) {
        int rg = wave * 2 + i;
        gload_lds16(kb  + (size_t)(rg * 8 + srow) * rs + scol,   &sK[0][rg * 512 + lane * 8]);
        gload_lds16(vtb + (size_t)(rg * 8 + srow) * TLEN + scol, &sVt[0][rg * 512 + lane * 8]);
    }

    float m_run = -1e30f, l_run = 0.0f;
    fx4 oacc[4];
    #pragma unroll
    for (int db = 0; db < 4; db++) oacc[db] = (fx4)0.0f;

    const int f0 = (lane >> 4) & 1;

    #pragma unroll 2
    for (int t = 0; t < 32; ++t) {
        const int buf = t & 1;
        __syncthreads();   // staging of buf drained; prior reads of buf^1 done

        // ---- prefetch next tile into buf^1 (async, drains at next barrier)
        if (t + 1 < 32) {
            const int kt = (t + 1) * 64;
            #pragma unroll
            for (int i = 0; i < 2; i++) {
                int rg = wave * 2 + i;
                gload_lds16(kb  + (size_t)(kt + rg * 8 + srow) * rs + scol,
                            &sK[buf ^ 1][rg * 512 + lane * 8]);
                gload_lds16(vtb + (size_t)(rg * 8 + srow) * TLEN + kt + scol,
                            &sVt[buf ^ 1][rg * 512 + lane * 8]);
            }
        }

        // ---- QK^T swapped: sacc[n] holds S[kv = n*16+fq*4+j][q = fr]
        fx4 sacc[4];
        #pragma unroll
        for (int n = 0; n < 4; n++) sacc[n] = (fx4)0.0f;
        __builtin_amdgcn_s_setprio(1);
        #pragma unroll
        for (int s = 0; s < 2; s++)
            #pragma unroll
            for (int n = 0; n < 4; n++) {
                bfx8 kF = *(const bfx8*)&sK[buf][(n * 16 + fr) * 64 + (((s * 4 + fq) ^ (fr & 7)) * 8)];
                sacc[n] = __builtin_amdgcn_mfma_f32_16x16x32_bf16(kF, qF[s], sacc[n], 0, 0, 0);
            }
        __builtin_amdgcn_s_setprio(0);

        // ---- online softmax, lane-local for q=fr (reduce over fq: masks 16,32)
        float t0 = fmaxf(fmaxf(sacc[0][0], sacc[0][1]), sacc[0][2]);
        float t1 = fmaxf(fmaxf(sacc[0][3], sacc[1][0]), sacc[1][1]);
        float t2 = fmaxf(fmaxf(sacc[1][2], sacc[1][3]), sacc[2][0]);
        float t3 = fmaxf(fmaxf(sacc[2][1], sacc[2][2]), sacc[2][3]);
        float t4 = fmaxf(fmaxf(sacc[3][0], sacc[3][1]), sacc[3][2]);
        float smax = fmaxf(fmaxf(fmaxf(t0, t1), t2), fmaxf(fmaxf(t3, t4), sacc[3][3]));
        smax = fmaxf(smax, __shfl_xor(smax, 16));
        smax = fmaxf(smax, __shfl_xor(smax, 32));
        if (!__all(smax <= m_run + 8.0f)) {        // defer-max: P bounded by 2^8
            float mnew = fmaxf(m_run, smax);
            float scal = __builtin_amdgcn_exp2f(m_run - mnew);
            l_run *= scal;
            #pragma unroll
            for (int db = 0; db < 4; db++) oacc[db] *= scal;
            m_run = mnew;
        }
        float p[4][4];
        float ps = 0.0f;
        #pragma unroll
        for (int n = 0; n < 4; n++)
            #pragma unroll
            for (int j = 0; j < 4; j++) {
                p[n][j] = __builtin_amdgcn_exp2f(sacc[n][j] - m_run);
                ps += p[n][j];
            }
        ps += __shfl_xor(ps, 16);
        ps += __shfl_xor(ps, 32);
        l_run += ps;

        // ---- pack P to bf16 pairs (v_cvt_pk), redistribute into PV B-operand layout.
        // permlane32_swap(A=u0, B=u1): A_new={l<32:u0[l]; l>=32:u1[l-32]},
        // B_new={l<32:u0[l+32]; l>=32:u1[l]}. Verified vs reference butterfly:
        // kp = f0 ? B : A,  z = f0 ? A : B,  rc = shfl_xor(z,16).
        unsigned int u[4][2];
        #pragma unroll
        for (int n = 0; n < 4; n++)
            #pragma unroll
            for (int h = 0; h < 2; h++)
                u[n][h] = cvtpk_bf16(p[n][2 * h], p[n][2 * h + 1]);
        unsigned int w[2][4];
        #pragma unroll
        for (int m = 0; m < 2; m++)
            #pragma unroll
            for (int h = 0; h < 2; h++) {
                unsigned int Aq = u[2 * m][h];       // u0 (vdst)
                unsigned int Bq = u[2 * m + 1][h];   // u1 (vsrc)
                asm("v_permlane32_swap_b32 %0, %1" : "+v"(Aq), "+v"(Bq));
                unsigned int kp = f0 ? Bq : Aq;
                unsigned int z  = f0 ? Aq : Bq;
                unsigned int rc = __shfl_xor((int)z, 16);
                w[m][h]     = f0 ? rc : kp;
                w[m][2 + h] = f0 ? kp : rc;
            }

        // ---- PV swapped: oacc[db] = O^T[d = db*16+fq*4+j][q = fr]
        __builtin_amdgcn_s_setprio(1);
        #pragma unroll
        for (int s = 0; s < 2; s++) {
            union { unsigned int ui[4]; bfx8 bf; } cv;
            cv.ui[0] = w[s][0]; cv.ui[1] = w[s][1]; cv.ui[2] = w[s][2]; cv.ui[3] = w[s][3];
            #pragma unroll
            for (int db = 0; db < 4; db++) {
                bfx8 vF = *(const bfx8*)&sVt[buf][(db * 16 + fr) * 64 + (((s * 4 + fq) ^ (fr & 7)) * 8)];
                oacc[db] = __builtin_amdgcn_mfma_f32_16x16x32_bf16(vF, cv.bf, oacc[db], 0, 0, 0);
            }
        }
        __builtin_amdgcn_s_setprio(0);
    }

    // ---- epilogue: O^T in regs -> ao row-major
    float invl = 1.0f / l_run;
    const int qrow = qt * 64 + wave * 16 + fr;
    unsigned short* aop = ao + (size_t)(b * TLEN + qrow) * 1024 + hh * 64 + fq * 4;
    #pragma unroll
    for (int db = 0; db < 4; db++) {
        usx4 o4;
        #pragma unroll
        for (int j = 0; j < 4; j++) o4[j] = f2bf(oacc[db][j] * invl);
        *(usx4*)(aop + db * 16) = o4;
    }
}

extern "C" void kernel_launch(void* const* d_in, const int* in_sizes, int n_in,
                              void* d_out, int out_size, void* d_ws, size_t ws_size,
                              hipStream_t stream) {
    const float* x    = (const float*)d_in[0];
    const float* wq   = (const float*)d_in[1];
    const float* wk   = (const float*)d_in[2];
    const float* wv   = (const float*)d_in[3];
    const float* wo   = (const float*)d_in[4];
    const float* lng  = (const float*)d_in[5];
    const float* lnb  = (const float*)d_in[6];
    const float* cosT = (const float*)d_in[7];
    const float* sinT = (const float*)d_in[8];

    char* ws = (char*)d_ws;
    unsigned short* wob  = (unsigned short*)(ws);                // 2 MB  [1024][1024] bf16
    unsigned short* wqkv = (unsigned short*)(ws + (2u  << 20));  // 6 MB  [3072][1024] bf16 (wq|wk|wv)
    unsigned short* hbuf = (unsigned short*)(ws + (8u  << 20));  // 8 MB  [4096][1024] bf16
    unsigned short* qk   = (unsigned short*)(ws + (16u << 20));  // 16 MB [4096][2048] bf16 (q|k)
    unsigned short* vtb  = (unsigned short*)(ws + (32u << 20));  // 8 MB  [32 bh][64 d][2048 t]
    unsigned short* ao   = (unsigned short*)(ws + (8u  << 20));  // aliases hbuf (dead after V gemm)

    ln_kernel<<<ROWS, 256, 0, stream>>>(x, lng, lnb, hbuf);
    wconv_kernel<<<1024, 256, 0, stream>>>(wq, wk, wv, wo, wqkv, wob);
    gemm_bt<0><<<dim3(32, 16), 256, 0, stream>>>(hbuf, wqkv, qk, 2048);                 // q|k
    gemm_bt<2><<<dim3(8, 32), 256, 0, stream>>>(wqkv + 2048 * 1024, hbuf, vtb, 0);      // V^T
    rope_kernel<<<8192, 256, 0, stream>>>(qk, cosT, sinT);
    attn_kernel<<<dim3(32, 32), 256, 0, stream>>>(qk, vtb, ao);
    gemm_bt<1><<<dim3(32, 8), 256, 0, stream>>>(ao, wob, (float*)d_out, 1024);
}

// Round 7
// 149.602 us; speedup vs baseline: 1.1755x; 1.0602x over previous
//
#include <hip/hip_runtime.h>
#include <hip/hip_bf16.h>

typedef __attribute__((ext_vector_type(4))) float          fx4;
typedef __attribute__((ext_vector_type(8))) __bf16         bfx8;
typedef __attribute__((ext_vector_type(8))) unsigned short usx8;
typedef __attribute__((ext_vector_type(4))) unsigned short usx4;

#define TLEN 2048
#define ROWS 4096   /* B*T */
#define D    1024

__device__ __forceinline__ float bf2f(unsigned short u) {
    union { unsigned int i; float f; } v; v.i = ((unsigned int)u) << 16; return v.f;
}
__device__ __forceinline__ unsigned short f2bf(float f) {
    union { float f; unsigned int i; } v; v.f = f;
    unsigned int r = v.i + 0x7fffu + ((v.i >> 16) & 1u);
    return (unsigned short)(r >> 16);
}
__device__ __forceinline__ unsigned int cvtpk_bf16(float lo, float hi) {
    unsigned int r;
    asm("v_cvt_pk_bf16_f32 %0, %1, %2" : "=v"(r) : "v"(lo), "v"(hi));
    return r;
}
__device__ __forceinline__ void gload_lds16(const unsigned short* g, unsigned short* l) {
    __builtin_amdgcn_global_load_lds((const __attribute__((address_space(1))) void*)g,
                                     (__attribute__((address_space(3))) void*)l, 16, 0, 0);
}

// ---------------- LayerNorm: fp32 x -> bf16 h ----------------
__global__ __launch_bounds__(256) void ln_kernel(const float* __restrict__ x,
                                                 const float* __restrict__ g,
                                                 const float* __restrict__ bta,
                                                 unsigned short* __restrict__ hout) {
    const int row = blockIdx.x, tid = threadIdx.x;
    fx4 v = ((const fx4*)(x + (size_t)row * D))[tid];
    float s  = v[0] + v[1] + v[2] + v[3];
    float s2 = v[0]*v[0] + v[1]*v[1] + v[2]*v[2] + v[3]*v[3];
    #pragma unroll
    for (int mk = 32; mk >= 1; mk >>= 1) { s += __shfl_xor(s, mk); s2 += __shfl_xor(s2, mk); }
    __shared__ float red[8];
    const int wave = tid >> 6, lane = tid & 63;
    if (lane == 0) { red[wave] = s; red[4 + wave] = s2; }
    __syncthreads();
    s  = red[0] + red[1] + red[2] + red[3];
    s2 = red[4] + red[5] + red[6] + red[7];
    float mu   = s * (1.0f / D);
    float var  = s2 * (1.0f / D) - mu * mu;
    float rstd = rsqrtf(var + 1e-5f);
    fx4 gv = ((const fx4*)g)[tid];
    fx4 bv = ((const fx4*)bta)[tid];
    usx4 o;
    #pragma unroll
    for (int j = 0; j < 4; j++) o[j] = f2bf((v[j] - mu) * rstd * gv[j] + bv[j]);
    ((usx4*)hout)[(size_t)row * 256 + tid] = o;
}

// ---------------- Weight convert: fp32 -> bf16, wq|wk|wv concat ----------------
__device__ __forceinline__ usx4 cvt4(fx4 a) {
    usx4 o;
    #pragma unroll
    for (int j = 0; j < 4; j++) o[j] = f2bf(a[j]);
    return o;
}
__global__ __launch_bounds__(256) void wconv_kernel(const float* __restrict__ wq, const float* __restrict__ wk,
                                                    const float* __restrict__ wv, const float* __restrict__ wo,
                                                    unsigned short* __restrict__ wqkv,
                                                    unsigned short* __restrict__ wob) {
    const int i = blockIdx.x * 256 + threadIdx.x;   // usx4 units, 262144 per matrix
    ((usx4*)wqkv)[i]          = cvt4(((const fx4*)wq)[i]);
    ((usx4*)wqkv)[262144 + i] = cvt4(((const fx4*)wk)[i]);
    ((usx4*)wqkv)[524288 + i] = cvt4(((const fx4*)wv)[i]);
    ((usx4*)wob)[i]           = cvt4(((const fx4*)wo)[i]);
}

// ---------------- Merged QK + V^T GEMM (768 blocks -> 3/CU) ----------------
// Blocks 0..511:  C[M=4096 tok][N=2048 qk] = hbuf * wqk^T, bf16 out, ldc 2048.
// Blocks 512..767: Vt-part — C[M=1024 d][N=4096 tok] = wv * hbuf^T, stored as
//                  Vt[(b*16 + d>>6)*64 + (d&63)][t] (coalesced along t).
__global__ __launch_bounds__(256) void qkvt_gemm(const unsigned short* __restrict__ hbuf,
                                                 const unsigned short* __restrict__ wqkv,
                                                 unsigned short* __restrict__ qkout,
                                                 unsigned short* __restrict__ vtout) {
    constexpr int K = 1024;
    __shared__ __align__(16) unsigned short As[128 * 32];
    __shared__ __align__(16) unsigned short Bs[128 * 32];
    const int tid = threadIdx.x, lane = tid & 63, wave = tid >> 6;
    const int fr = lane & 15, fq = lane >> 4;
    const int wr = wave >> 1, wc = wave & 1;

    const int id = blockIdx.x;
    const bool isqk = id < 512;
    int bm, bn;
    const unsigned short *Ab, *Bb;
    if (isqk) {
        bm = id & 31; bn = id >> 5;                                   // 32 x 16
        Ab = hbuf + (size_t)(bm * 128) * K;
        Bb = wqkv + (size_t)(bn * 128) * K;
    } else {
        int j = id - 512; bm = j & 7; bn = j >> 3;                    // 8 x 32
        Ab = wqkv + (size_t)(2048 * 1024) + (size_t)(bm * 128) * K;   // wv
        Bb = hbuf + (size_t)(bn * 128) * K;
    }

    const int str0 = wave * 32 + (lane >> 2);
    const int stc  = (lane & 3) * 8;

    fx4 acc[4][4];
    #pragma unroll
    for (int m = 0; m < 4; m++)
        #pragma unroll
        for (int n = 0; n < 4; n++) acc[m][n] = (fx4)0.0f;

    for (int kt = 0; kt < K; kt += 32) {
        gload_lds16(Ab + (size_t)str0 * K + kt + stc,        &As[str0 * 32 + stc]);
        gload_lds16(Ab + (size_t)(str0 + 16) * K + kt + stc, &As[(str0 + 16) * 32 + stc]);
        gload_lds16(Bb + (size_t)str0 * K + kt + stc,        &Bs[str0 * 32 + stc]);
        gload_lds16(Bb + (size_t)(str0 + 16) * K + kt + stc, &Bs[(str0 + 16) * 32 + stc]);
        __syncthreads();
        bfx8 aF[4], bF[4];
        #pragma unroll
        for (int m = 0; m < 4; m++) aF[m] = *(const bfx8*)&As[(wr * 64 + m * 16 + fr) * 32 + fq * 8];
        #pragma unroll
        for (int n = 0; n < 4; n++) bF[n] = *(const bfx8*)&Bs[(wc * 64 + n * 16 + fr) * 32 + fq * 8];
        #pragma unroll
        for (int m = 0; m < 4; m++)
            #pragma unroll
            for (int n = 0; n < 4; n++)
                acc[m][n] = __builtin_amdgcn_mfma_f32_16x16x32_bf16(aF[m], bF[n], acc[m][n], 0, 0, 0);
        __syncthreads();
    }

    const int row0 = bm * 128 + wr * 64 + fq * 4;
    const int col0 = bn * 128 + wc * 64 + fr;
    if (isqk) {
        #pragma unroll
        for (int m = 0; m < 4; m++)
            #pragma unroll
            for (int n = 0; n < 4; n++)
                #pragma unroll
                for (int j = 0; j < 4; j++)
                    qkout[(size_t)(row0 + m * 16 + j) * 2048 + col0 + n * 16] = f2bf(acc[m][n][j]);
    } else {
        const int bb = bn >> 4;
        #pragma unroll
        for (int m = 0; m < 4; m++)
            #pragma unroll
            for (int n = 0; n < 4; n++) {
                const int t = (col0 + n * 16) & (TLEN - 1);
                #pragma unroll
                for (int j = 0; j < 4; j++) {
                    const int d = row0 + m * 16 + j;
                    vtout[(((size_t)(bb * 16 + (d >> 6)) * 64) + (d & 63)) * TLEN + t] = f2bf(acc[m][n][j]);
                }
            }
    }
}

// ---------------- Output GEMM: 128x64 tile, 512 blocks, f32 out ----------------
__global__ __launch_bounds__(256) void gemm_out64(const unsigned short* __restrict__ A,
                                                  const unsigned short* __restrict__ B,
                                                  float* __restrict__ C) {
    constexpr int K = 1024;
    __shared__ __align__(16) unsigned short As[128 * 32];
    __shared__ __align__(16) unsigned short Bs[64 * 32];
    const int tid = threadIdx.x, lane = tid & 63, wave = tid >> 6;
    const int fr = lane & 15, fq = lane >> 4;
    const int bm = blockIdx.x, bn = blockIdx.y;
    const int wr = wave >> 1, wc = wave & 1;

    const int strA = wave * 32 + (lane >> 2);
    const int strB = wave * 16 + (lane >> 2);
    const int stc  = (lane & 3) * 8;
    const unsigned short* Ab = A + (size_t)(bm * 128) * K;
    const unsigned short* Bb = B + (size_t)(bn * 64) * K;

    fx4 acc[4][2];
    #pragma unroll
    for (int m = 0; m < 4; m++)
        #pragma unroll
        for (int n = 0; n < 2; n++) acc[m][n] = (fx4)0.0f;

    for (int kt = 0; kt < K; kt += 32) {
        gload_lds16(Ab + (size_t)strA * K + kt + stc,        &As[strA * 32 + stc]);
        gload_lds16(Ab + (size_t)(strA + 16) * K + kt + stc, &As[(strA + 16) * 32 + stc]);
        gload_lds16(Bb + (size_t)strB * K + kt + stc,        &Bs[strB * 32 + stc]);
        __syncthreads();
        bfx8 aF[4], bF[2];
        #pragma unroll
        for (int m = 0; m < 4; m++) aF[m] = *(const bfx8*)&As[(wr * 64 + m * 16 + fr) * 32 + fq * 8];
        #pragma unroll
        for (int n = 0; n < 2; n++) bF[n] = *(const bfx8*)&Bs[(wc * 32 + n * 16 + fr) * 32 + fq * 8];
        #pragma unroll
        for (int m = 0; m < 4; m++)
            #pragma unroll
            for (int n = 0; n < 2; n++)
                acc[m][n] = __builtin_amdgcn_mfma_f32_16x16x32_bf16(aF[m], bF[n], acc[m][n], 0, 0, 0);
        __syncthreads();
    }

    const int row0 = bm * 128 + wr * 64 + fq * 4;
    const int col0 = bn * 64 + wc * 32 + fr;
    #pragma unroll
    for (int m = 0; m < 4; m++)
        #pragma unroll
        for (int n = 0; n < 2; n++)
            #pragma unroll
            for (int j = 0; j < 4; j++)
                C[(size_t)(row0 + m * 16 + j) * 1024 + col0 + n * 16] = acc[m][n][j];
}

// ---------------- RoPE in-place on q,k (q also pre-scaled by 0.125*log2e) ----------------
__global__ __launch_bounds__(256) void rope_kernel(unsigned short* __restrict__ qk,
                                                   const float* __restrict__ cosT,
                                                   const float* __restrict__ sinT) {
    int idx = blockIdx.x * 256 + threadIdx.x;   // 4096 rows * 512 pairs
    int row = idx >> 9;
    int p   = idx & 511;
    int head = p >> 5, pi = p & 31;
    int t = row & (TLEN - 1);
    float c = cosT[t * 32 + pi], s = sinT[t * 32 + pi];
    size_t qoff = (size_t)row * 2048 + head * 64 + pi * 2;
    const float QS = 0.125f * 1.44269504088896f;   // scale * log2(e): softmax via exp2
    unsigned int uq = *(const unsigned int*)&qk[qoff];
    float x0 = bf2f((unsigned short)(uq & 0xffff));
    float x1 = bf2f((unsigned short)(uq >> 16));
    unsigned int r0 = f2bf((x0 * c - x1 * s) * QS);
    unsigned int r1 = f2bf((x0 * s + x1 * c) * QS);
    *(unsigned int*)&qk[qoff] = r0 | (r1 << 16);
    size_t koff = qoff + 1024;
    unsigned int uk = *(const unsigned int*)&qk[koff];
    x0 = bf2f((unsigned short)(uk & 0xffff));
    x1 = bf2f((unsigned short)(uk >> 16));
    r0 = f2bf(x0 * c - x1 * s);
    r1 = f2bf(x0 * s + x1 * c);
    *(unsigned int*)&qk[koff] = r0 | (r1 << 16);
}

// ---------------- Flash attention (full, non-causal), bf16 MFMA ----------------
// 4 waves; wave owns 16 q-rows; KVBLK=64. Swapped QK^T with C-init = -m_run
// (P = exp2(sacc) directly, m_run starts at 0), defer-max, l via ones-row MFMA,
// in-register P via permlane32_swap butterfly, swapped PV. K and pre-transposed
// V^T staged via global_load_lds with both-sides XOR swizzle; double-buffered.
__global__ __launch_bounds__(256) void attn_kernel(const unsigned short* __restrict__ qk,
                                                   const unsigned short* __restrict__ vt,
                                                   unsigned short* __restrict__ ao) {
    // XCD swizzle: 1024 blocks -> each XCD hosts 4 consecutive bh groups
    const int flat = blockIdx.x + (blockIdx.y << 5);
    const int sid  = (flat & 7) * 128 + (flat >> 3);
    const int qt = sid & 31, bh = sid >> 5;
    const int b = bh >> 4, hh = bh & 15;
    const int tid = threadIdx.x, lane = tid & 63, wave = tid >> 6;
    const int fr = lane & 15, fq = lane >> 4;

    __shared__ __align__(16) unsigned short sK[2][64 * 64];   // swizzled K tile
    __shared__ __align__(16) unsigned short sVt[2][64 * 64];  // swizzled V^T tile

    const size_t rs = 2048;
    const unsigned short* qb  = qk + (size_t)b * TLEN * rs + hh * 64;
    const unsigned short* kb  = qb + 1024;
    const unsigned short* vtb = vt + (size_t)bh * (64 * TLEN);

    bfx8 qF[2];
    {
        int qrow = qt * 64 + wave * 16 + fr;
        const unsigned short* qp = qb + (size_t)qrow * rs + fq * 8;
        qF[0] = *(const bfx8*)qp;
        qF[1] = *(const bfx8*)(qp + 32);
    }
    union { unsigned short us[8]; bfx8 bf; } ones_u;
    #pragma unroll
    for (int i = 0; i < 8; i++) ones_u.us[i] = 0x3F80;   // bf16 1.0

    // staging geometry: wave stages row-groups rg=wave*2+{0,1} (8 rows each);
    // LDS dest linear (lane*16B), global source col pre-swizzled (both-sides XOR).
    const int srow = lane >> 3;
    const int scol = ((lane & 7) ^ srow) * 8;

    // ---- prologue: stage tile 0 into buf 0
    #pragma unroll
    for (int i = 0; i < 2; i++) {
        int rg = wave * 2 + i;
        gload_lds16(kb  + (size_t)(rg * 8 + srow) * rs + scol,   &sK[0][rg * 512 + lane * 8]);
        gload_lds16(vtb + (size_t)(rg * 8 + srow) * TLEN + scol, &sVt[0][rg * 512 + lane * 8]);
    }

    float m_run = 0.0f;           // defer-max baseline (scores rarely exceed 8)
    fx4 oacc[4];
    fx4 oextra = (fx4)0.0f;       // ones-row accumulator = running l (rescaled with oacc)
    #pragma unroll
    for (int db = 0; db < 4; db++) oacc[db] = (fx4)0.0f;

    const int f0 = (lane >> 4) & 1;

    #pragma unroll 2
    for (int t = 0; t < 32; ++t) {
        const int buf = t & 1;
        __syncthreads();   // staging of buf drained; prior reads of buf^1 done

        // ---- prefetch next tile into buf^1 (async, drains at next barrier)
        if (t + 1 < 32) {
            const int kt = (t + 1) * 64;
            #pragma unroll
            for (int i = 0; i < 2; i++) {
                int rg = wave * 2 + i;
                gload_lds16(kb  + (size_t)(kt + rg * 8 + srow) * rs + scol,
                            &sK[buf ^ 1][rg * 512 + lane * 8]);
                gload_lds16(vtb + (size_t)(rg * 8 + srow) * TLEN + kt + scol,
                            &sVt[buf ^ 1][rg * 512 + lane * 8]);
            }
        }

        // ---- QK^T swapped, C-init = -m_run: sacc[n][j] = S[kv][q=fr] - m_run
        fx4 sacc[4];
        #pragma unroll
        for (int n = 0; n < 4; n++) sacc[n] = (fx4)(-m_run);
        __builtin_amdgcn_s_setprio(1);
        #pragma unroll
        for (int s = 0; s < 2; s++)
            #pragma unroll
            for (int n = 0; n < 4; n++) {
                bfx8 kF = *(const bfx8*)&sK[buf][(n * 16 + fr) * 64 + (((s * 4 + fq) ^ (fr & 7)) * 8)];
                sacc[n] = __builtin_amdgcn_mfma_f32_16x16x32_bf16(kF, qF[s], sacc[n], 0, 0, 0);
            }
        __builtin_amdgcn_s_setprio(0);

        // ---- relative row max (reduce over fq: masks 16,32)
        float t0 = fmaxf(fmaxf(sacc[0][0], sacc[0][1]), sacc[0][2]);
        float t1 = fmaxf(fmaxf(sacc[0][3], sacc[1][0]), sacc[1][1]);
        float t2 = fmaxf(fmaxf(sacc[1][2], sacc[1][3]), sacc[2][0]);
        float t3 = fmaxf(fmaxf(sacc[2][1], sacc[2][2]), sacc[2][3]);
        float t4 = fmaxf(fmaxf(sacc[3][0], sacc[3][1]), sacc[3][2]);
        float smax = fmaxf(fmaxf(fmaxf(t0, t1), t2), fmaxf(fmaxf(t3, t4), sacc[3][3]));
        smax = fmaxf(smax, __shfl_xor(smax, 16));
        smax = fmaxf(smax, __shfl_xor(smax, 32));
        if (!__all(smax <= 8.0f)) {            // defer-max: P bounded by 2^8
            float delta = fmaxf(smax, 0.0f);   // per-q-row, uniform across fq
            float scal = __builtin_amdgcn_exp2f(-delta);
            m_run += delta;
            #pragma unroll
            for (int n = 0; n < 4; n++)
                #pragma unroll
                for (int j = 0; j < 4; j++) sacc[n][j] -= delta;
            #pragma unroll
            for (int db = 0; db < 4; db++) oacc[db] *= scal;
            oextra *= scal;
        }
        float p[4][4];
        #pragma unroll
        for (int n = 0; n < 4; n++)
            #pragma unroll
            for (int j = 0; j < 4; j++)
                p[n][j] = __builtin_amdgcn_exp2f(sacc[n][j]);

        // ---- pack P to bf16 pairs (v_cvt_pk), redistribute into PV B-operand layout.
        // permlane32_swap(A=u0, B=u1): A_new={l<32:u0[l]; l>=32:u1[l-32]},
        // B_new={l<32:u0[l+32]; l>=32:u1[l]}.  kp = f0?B:A, z = f0?A:B, rc = shfl16(z).
        unsigned int u[4][2];
        #pragma unroll
        for (int n = 0; n < 4; n++)
            #pragma unroll
            for (int h = 0; h < 2; h++)
                u[n][h] = cvtpk_bf16(p[n][2 * h], p[n][2 * h + 1]);
        unsigned int w[2][4];
        #pragma unroll
        for (int m = 0; m < 2; m++)
            #pragma unroll
            for (int h = 0; h < 2; h++) {
                unsigned int Aq = u[2 * m][h];       // u0 (vdst)
                unsigned int Bq = u[2 * m + 1][h];   // u1 (vsrc)
                asm("v_permlane32_swap_b32 %0, %1" : "+v"(Aq), "+v"(Bq));
                unsigned int kp = f0 ? Bq : Aq;
                unsigned int z  = f0 ? Aq : Bq;
                unsigned int rc = __shfl_xor((int)z, 16);
                w[m][h]     = f0 ? rc : kp;
                w[m][2 + h] = f0 ? kp : rc;
            }

        // ---- PV swapped + ones-row (l): oacc[db] = O^T[d][q=fr], oextra = l[q=fr]
        __builtin_amdgcn_s_setprio(1);
        #pragma unroll
        for (int s = 0; s < 2; s++) {
            union { unsigned int ui[4]; bfx8 bf; } cv;
            cv.ui[0] = w[s][0]; cv.ui[1] = w[s][1]; cv.ui[2] = w[s][2]; cv.ui[3] = w[s][3];
            #pragma unroll
            for (int db = 0; db < 4; db++) {
                bfx8 vF = *(const bfx8*)&sVt[buf][(db * 16 + fr) * 64 + (((s * 4 + fq) ^ (fr & 7)) * 8)];
                oacc[db] = __builtin_amdgcn_mfma_f32_16x16x32_bf16(vF, cv.bf, oacc[db], 0, 0, 0);
            }
            oextra = __builtin_amdgcn_mfma_f32_16x16x32_bf16(ones_u.bf, cv.bf, oextra, 0, 0, 0);
        }
        __builtin_amdgcn_s_setprio(0);
    }

    // ---- epilogue: O^T in regs -> ao row-major (all oextra[j] rows identical)
    float invl = 1.0f / oextra[0];
    const int qrow = qt * 64 + wave * 16 + fr;
    unsigned short* aop = ao + (size_t)(b * TLEN + qrow) * 1024 + hh * 64 + fq * 4;
    #pragma unroll
    for (int db = 0; db < 4; db++) {
        usx4 o4;
        #pragma unroll
        for (int j = 0; j < 4; j++) o4[j] = f2bf(oacc[db][j] * invl);
        *(usx4*)(aop + db * 16) = o4;
    }
}

extern "C" void kernel_launch(void* const* d_in, const int* in_sizes, int n_in,
                              void* d_out, int out_size, void* d_ws, size_t ws_size,
                              hipStream_t stream) {
    const float* x    = (const float*)d_in[0];
    const float* wq   = (const float*)d_in[1];
    const float* wk   = (const float*)d_in[2];
    const float* wv   = (const float*)d_in[3];
    const float* wo   = (const float*)d_in[4];
    const float* lng  = (const float*)d_in[5];
    const float* lnb  = (const float*)d_in[6];
    const float* cosT = (const float*)d_in[7];
    const float* sinT = (const float*)d_in[8];

    char* ws = (char*)d_ws;
    unsigned short* wob  = (unsigned short*)(ws);                // 2 MB  [1024][1024] bf16
    unsigned short* wqkv = (unsigned short*)(ws + (2u  << 20));  // 6 MB  [3072][1024] bf16 (wq|wk|wv)
    unsigned short* hbuf = (unsigned short*)(ws + (8u  << 20));  // 8 MB  [4096][1024] bf16
    unsigned short* qk   = (unsigned short*)(ws + (16u << 20));  // 16 MB [4096][2048] bf16 (q|k)
    unsigned short* vtb  = (unsigned short*)(ws + (32u << 20));  // 8 MB  [32 bh][64 d][2048 t]
    unsigned short* ao   = (unsigned short*)(ws + (8u  << 20));  // aliases hbuf (dead after qkvt)

    ln_kernel<<<ROWS, 256, 0, stream>>>(x, lng, lnb, hbuf);
    wconv_kernel<<<1024, 256, 0, stream>>>(wq, wk, wv, wo, wqkv, wob);
    qkvt_gemm<<<768, 256, 0, stream>>>(hbuf, wqkv, qk, vtb);
    rope_kernel<<<8192, 256, 0, stream>>>(qk, cosT, sinT);
    attn_kernel<<<dim3(32, 32), 256, 0, stream>>>(qk, vtb, ao);
    gemm_out64<<<dim3(32, 16), 256, 0, stream>>>(ao, wob, (float*)d_out);
}

// Round 8
// 133.855 us; speedup vs baseline: 1.3138x; 1.1176x over previous
//
#include <hip/hip_runtime.h>
#include <hip/hip_bf16.h>

typedef __attribute__((ext_vector_type(4))) float          fx4;
typedef __attribute__((ext_vector_type(8))) __bf16         bfx8;
typedef __attribute__((ext_vector_type(8))) unsigned short usx8;
typedef __attribute__((ext_vector_type(4))) unsigned short usx4;

#define TLEN 2048
#define ROWS 4096   /* B*T */
#define D    1024

__device__ __forceinline__ float bf2f(unsigned short u) {
    union { unsigned int i; float f; } v; v.i = ((unsigned int)u) << 16; return v.f;
}
__device__ __forceinline__ unsigned short f2bf(float f) {
    union { float f; unsigned int i; } v; v.f = f;
    unsigned int r = v.i + 0x7fffu + ((v.i >> 16) & 1u);
    return (unsigned short)(r >> 16);
}
__device__ __forceinline__ unsigned int cvtpk_bf16(float lo, float hi) {
    unsigned int r;
    asm("v_cvt_pk_bf16_f32 %0, %1, %2" : "=v"(r) : "v"(lo), "v"(hi));
    return r;
}
__device__ __forceinline__ float fast_cos(float a) {
    float r; asm("v_cos_f32 %0, %1" : "=v"(r) : "v"(a)); return r;
}
__device__ __forceinline__ float fast_sin(float a) {
    float r; asm("v_sin_f32 %0, %1" : "=v"(r) : "v"(a)); return r;
}
__device__ __forceinline__ void gload_lds16(const unsigned short* g, unsigned short* l) {
    __builtin_amdgcn_global_load_lds((const __attribute__((address_space(1))) void*)g,
                                     (__attribute__((address_space(3))) void*)l, 16, 0, 0);
}

// ---------------- LayerNorm: fp32 x -> bf16 h ----------------
__global__ __launch_bounds__(256) void ln_kernel(const float* __restrict__ x,
                                                 const float* __restrict__ g,
                                                 const float* __restrict__ bta,
                                                 unsigned short* __restrict__ hout) {
    const int row = blockIdx.x, tid = threadIdx.x;
    fx4 v = ((const fx4*)(x + (size_t)row * D))[tid];
    float s  = v[0] + v[1] + v[2] + v[3];
    float s2 = v[0]*v[0] + v[1]*v[1] + v[2]*v[2] + v[3]*v[3];
    #pragma unroll
    for (int mk = 32; mk >= 1; mk >>= 1) { s += __shfl_xor(s, mk); s2 += __shfl_xor(s2, mk); }
    __shared__ float red[8];
    const int wave = tid >> 6, lane = tid & 63;
    if (lane == 0) { red[wave] = s; red[4 + wave] = s2; }
    __syncthreads();
    s  = red[0] + red[1] + red[2] + red[3];
    s2 = red[4] + red[5] + red[6] + red[7];
    float mu   = s * (1.0f / D);
    float var  = s2 * (1.0f / D) - mu * mu;
    float rstd = rsqrtf(var + 1e-5f);
    fx4 gv = ((const fx4*)g)[tid];
    fx4 bv = ((const fx4*)bta)[tid];
    usx4 o;
    #pragma unroll
    for (int j = 0; j < 4; j++) o[j] = f2bf((v[j] - mu) * rstd * gv[j] + bv[j]);
    ((usx4*)hout)[(size_t)row * 256 + tid] = o;
}

// ---------------- Weight convert: fp32 -> bf16, wq|wk|wv concat ----------------
__device__ __forceinline__ usx4 cvt4(fx4 a) {
    usx4 o;
    #pragma unroll
    for (int j = 0; j < 4; j++) o[j] = f2bf(a[j]);
    return o;
}
__global__ __launch_bounds__(256) void wconv_kernel(const float* __restrict__ wq, const float* __restrict__ wk,
                                                    const float* __restrict__ wv, const float* __restrict__ wo,
                                                    unsigned short* __restrict__ wqkv,
                                                    unsigned short* __restrict__ wob) {
    const int i = blockIdx.x * 256 + threadIdx.x;   // usx4 units, 262144 per matrix
    ((usx4*)wqkv)[i]          = cvt4(((const fx4*)wq)[i]);
    ((usx4*)wqkv)[262144 + i] = cvt4(((const fx4*)wk)[i]);
    ((usx4*)wqkv)[524288 + i] = cvt4(((const fx4*)wv)[i]);
    ((usx4*)wob)[i]           = cvt4(((const fx4*)wo)[i]);
}

// ---------------- Merged QK + V^T GEMM (768 blocks -> 3/CU) ----------------
// Blocks 0..511: C[tok][2048 qk] = hbuf * wqk^T with FUSED RoPE (+ QS on q), bf16.
// Blocks 512..767: Vt — C[d][tok] = wv * hbuf^T stored to Vt[(b*16+d>>6)*64+(d&63)][t']
//   with within-64-token permutation t' = pi^{-1}(t): position k holds token
//   pi(k) = (2s+r2)*16 + fq*4 + j  for k = s*32+fq*8+r2*4+j  (kills attn's P-butterfly).
__global__ __launch_bounds__(256) void qkvt_gemm(const unsigned short* __restrict__ hbuf,
                                                 const unsigned short* __restrict__ wqkv,
                                                 unsigned short* __restrict__ qkout,
                                                 unsigned short* __restrict__ vtout) {
    constexpr int K = 1024;
    __shared__ __align__(16) unsigned short As[128 * 32];
    __shared__ __align__(16) unsigned short Bs[128 * 32];
    const int tid = threadIdx.x, lane = tid & 63, wave = tid >> 6;
    const int fr = lane & 15, fq = lane >> 4;
    const int wr = wave >> 1, wc = wave & 1;

    const int id = blockIdx.x;
    const bool isqk = id < 512;
    int bm, bn;
    const unsigned short *Ab, *Bb;
    if (isqk) {
        bm = id & 31; bn = id >> 5;                                   // 32 x 16
        Ab = hbuf + (size_t)(bm * 128) * K;
        Bb = wqkv + (size_t)(bn * 128) * K;
    } else {
        int j = id - 512; bm = j & 7; bn = j >> 3;                    // 8 x 32
        Ab = wqkv + (size_t)(2048 * 1024) + (size_t)(bm * 128) * K;   // wv
        Bb = hbuf + (size_t)(bn * 128) * K;
    }

    const int str0 = wave * 32 + (lane >> 2);
    const int stc  = (lane & 3) * 8;

    fx4 acc[4][4];
    #pragma unroll
    for (int m = 0; m < 4; m++)
        #pragma unroll
        for (int n = 0; n < 4; n++) acc[m][n] = (fx4)0.0f;

    for (int kt = 0; kt < K; kt += 32) {
        gload_lds16(Ab + (size_t)str0 * K + kt + stc,        &As[str0 * 32 + stc]);
        gload_lds16(Ab + (size_t)(str0 + 16) * K + kt + stc, &As[(str0 + 16) * 32 + stc]);
        gload_lds16(Bb + (size_t)str0 * K + kt + stc,        &Bs[str0 * 32 + stc]);
        gload_lds16(Bb + (size_t)(str0 + 16) * K + kt + stc, &Bs[(str0 + 16) * 32 + stc]);
        __syncthreads();
        bfx8 aF[4], bF[4];
        #pragma unroll
        for (int m = 0; m < 4; m++) aF[m] = *(const bfx8*)&As[(wr * 64 + m * 16 + fr) * 32 + fq * 8];
        #pragma unroll
        for (int n = 0; n < 4; n++) bF[n] = *(const bfx8*)&Bs[(wc * 64 + n * 16 + fr) * 32 + fq * 8];
        #pragma unroll
        for (int m = 0; m < 4; m++)
            #pragma unroll
            for (int n = 0; n < 4; n++)
                acc[m][n] = __builtin_amdgcn_mfma_f32_16x16x32_bf16(aF[m], bF[n], acc[m][n], 0, 0, 0);
        __syncthreads();
    }

    const int row0 = bm * 128 + wr * 64 + fq * 4;
    const int col0 = bn * 128 + wc * 64 + fr;
    if (isqk) {
        // fused RoPE: feature pairs (2i,2i+1) live in adjacent lanes (fr even/odd).
        // pi = head-feature/2 = n*8 + (fr>>1); angle in revolutions:
        // f_rev = theta^(-pi/32) / (2*pi) = exp2(-pi*log2(1e4)/32 - log2(2pi)).
        const float QS = 0.125f * 1.44269504088896f;
        const bool isq = bn < 8;
        const float sgn = (fr & 1) ? 1.0f : -1.0f;
        float fp[4];
        #pragma unroll
        for (int n = 0; n < 4; n++) {
            float pif = (float)(n * 8 + (fr >> 1));
            fp[n] = __builtin_amdgcn_exp2f(fmaf(pif, -0.415241011861f, -2.651496129472f));
        }
        #pragma unroll
        for (int m = 0; m < 4; m++) {
            const int rbase = row0 + m * 16;
            const float tf = (float)(rbase & (TLEN - 1));
            #pragma unroll
            for (int n = 0; n < 4; n++) {
                #pragma unroll
                for (int j = 0; j < 4; j++) {
                    float a = __builtin_amdgcn_fractf((tf + (float)j) * fp[n]);
                    float c = fast_cos(a), s = fast_sin(a);
                    float self = acc[m][n][j];
                    float other = __shfl_xor(self, 1);
                    float o = self * c + other * (sgn * s);
                    if (isq) o *= QS;
                    qkout[(size_t)(rbase + j) * 2048 + col0 + n * 16] = f2bf(o);
                }
            }
        }
    } else {
        const int bb = bn >> 4;
        // permuted within-64 column: t_w = n*16+fr  ->  (n>>1)*32+(fr>>2)*8+(n&1)*4+(fr&3)
        #pragma unroll
        for (int m = 0; m < 4; m++)
            #pragma unroll
            for (int n = 0; n < 4; n++) {
                const int t = (col0 + n * 16) & (TLEN - 1);
                const int tp = (t & ~63) | ((n >> 1) * 32 + ((fr >> 2)) * 8 + ((n & 1)) * 4 + (fr & 3));
                #pragma unroll
                for (int j = 0; j < 4; j++) {
                    const int d = row0 + m * 16 + j;
                    vtout[(((size_t)(bb * 16 + (d >> 6)) * 64) + (d & 63)) * TLEN + tp] = f2bf(acc[m][n][j]);
                }
            }
    }
}

// ---------------- Output GEMM: 128x64 tile, 512 blocks, f32 out ----------------
__global__ __launch_bounds__(256) void gemm_out64(const unsigned short* __restrict__ A,
                                                  const unsigned short* __restrict__ B,
                                                  float* __restrict__ C) {
    constexpr int K = 1024;
    __shared__ __align__(16) unsigned short As[128 * 32];
    __shared__ __align__(16) unsigned short Bs[64 * 32];
    const int tid = threadIdx.x, lane = tid & 63, wave = tid >> 6;
    const int fr = lane & 15, fq = lane >> 4;
    const int bm = blockIdx.x, bn = blockIdx.y;
    const int wr = wave >> 1, wc = wave & 1;

    const int strA = wave * 32 + (lane >> 2);
    const int strB = wave * 16 + (lane >> 2);
    const int stc  = (lane & 3) * 8;
    const unsigned short* Ab = A + (size_t)(bm * 128) * K;
    const unsigned short* Bb = B + (size_t)(bn * 64) * K;

    fx4 acc[4][2];
    #pragma unroll
    for (int m = 0; m < 4; m++)
        #pragma unroll
        for (int n = 0; n < 2; n++) acc[m][n] = (fx4)0.0f;

    for (int kt = 0; kt < K; kt += 32) {
        gload_lds16(Ab + (size_t)strA * K + kt + stc,        &As[strA * 32 + stc]);
        gload_lds16(Ab + (size_t)(strA + 16) * K + kt + stc, &As[(strA + 16) * 32 + stc]);
        gload_lds16(Bb + (size_t)strB * K + kt + stc,        &Bs[strB * 32 + stc]);
        __syncthreads();
        bfx8 aF[4], bF[2];
        #pragma unroll
        for (int m = 0; m < 4; m++) aF[m] = *(const bfx8*)&As[(wr * 64 + m * 16 + fr) * 32 + fq * 8];
        #pragma unroll
        for (int n = 0; n < 2; n++) bF[n] = *(const bfx8*)&Bs[(wc * 32 + n * 16 + fr) * 32 + fq * 8];
        #pragma unroll
        for (int m = 0; m < 4; m++)
            #pragma unroll
            for (int n = 0; n < 2; n++)
                acc[m][n] = __builtin_amdgcn_mfma_f32_16x16x32_bf16(aF[m], bF[n], acc[m][n], 0, 0, 0);
        __syncthreads();
    }

    const int row0 = bm * 128 + wr * 64 + fq * 4;
    const int col0 = bn * 64 + wc * 32 + fr;
    #pragma unroll
    for (int m = 0; m < 4; m++)
        #pragma unroll
        for (int n = 0; n < 2; n++)
            #pragma unroll
            for (int j = 0; j < 4; j++)
                C[(size_t)(row0 + m * 16 + j) * 1024 + col0 + n * 16] = acc[m][n][j];
}

// ---------------- Flash attention (full, non-causal), bf16 MFMA ----------------
// 4 waves; wave owns 16 q-rows; KVBLK=64. Swapped QK^T with C-init = -m_run,
// defer-max, l via ones-row MFMA. P feeds PV directly (no cross-lane movement):
// V token order was pre-permuted at Vt generation so PV's B-operand slot
// k = s*32+fq*8+r2*4+j wants exactly this lane's p[2s+r2][j].
__global__ __launch_bounds__(256) void attn_kernel(const unsigned short* __restrict__ qk,
                                                   const unsigned short* __restrict__ vt,
                                                   unsigned short* __restrict__ ao) {
    // XCD swizzle: 1024 blocks -> each XCD hosts 4 consecutive bh groups
    const int flat = blockIdx.x + (blockIdx.y << 5);
    const int sid  = (flat & 7) * 128 + (flat >> 3);
    const int qt = sid & 31, bh = sid >> 5;
    const int b = bh >> 4, hh = bh & 15;
    const int tid = threadIdx.x, lane = tid & 63, wave = tid >> 6;
    const int fr = lane & 15, fq = lane >> 4;

    __shared__ __align__(16) unsigned short sK[2][64 * 64];   // swizzled K tile
    __shared__ __align__(16) unsigned short sVt[2][64 * 64];  // swizzled V^T tile

    const size_t rs = 2048;
    const unsigned short* qb  = qk + (size_t)b * TLEN * rs + hh * 64;
    const unsigned short* kb  = qb + 1024;
    const unsigned short* vtb = vt + (size_t)bh * (64 * TLEN);

    bfx8 qF[2];
    {
        int qrow = qt * 64 + wave * 16 + fr;
        const unsigned short* qp = qb + (size_t)qrow * rs + fq * 8;
        qF[0] = *(const bfx8*)qp;
        qF[1] = *(const bfx8*)(qp + 32);
    }
    union { unsigned short us[8]; bfx8 bf; } ones_u;
    #pragma unroll
    for (int i = 0; i < 8; i++) ones_u.us[i] = 0x3F80;   // bf16 1.0

    // staging geometry: wave stages row-groups rg=wave*2+{0,1} (8 rows each);
    // LDS dest linear (lane*16B), global source col pre-swizzled (both-sides XOR).
    const int srow = lane >> 3;
    const int scol = ((lane & 7) ^ srow) * 8;

    // ---- prologue: stage tile 0 into buf 0
    #pragma unroll
    for (int i = 0; i < 2; i++) {
        int rg = wave * 2 + i;
        gload_lds16(kb  + (size_t)(rg * 8 + srow) * rs + scol,   &sK[0][rg * 512 + lane * 8]);
        gload_lds16(vtb + (size_t)(rg * 8 + srow) * TLEN + scol, &sVt[0][rg * 512 + lane * 8]);
    }

    float m_run = 0.0f;           // defer-max baseline (scores rarely exceed 8)
    fx4 oacc[4];
    fx4 oextra = (fx4)0.0f;       // ones-row accumulator = running l (rescaled with oacc)
    #pragma unroll
    for (int db = 0; db < 4; db++) oacc[db] = (fx4)0.0f;

    #pragma unroll 2
    for (int t = 0; t < 32; ++t) {
        const int buf = t & 1;
        __syncthreads();   // staging of buf drained; prior reads of buf^1 done

        // ---- prefetch next tile into buf^1 (async, drains at next barrier)
        if (t + 1 < 32) {
            const int kt = (t + 1) * 64;
            #pragma unroll
            for (int i = 0; i < 2; i++) {
                int rg = wave * 2 + i;
                gload_lds16(kb  + (size_t)(kt + rg * 8 + srow) * rs + scol,
                            &sK[buf ^ 1][rg * 512 + lane * 8]);
                gload_lds16(vtb + (size_t)(rg * 8 + srow) * TLEN + kt + scol,
                            &sVt[buf ^ 1][rg * 512 + lane * 8]);
            }
        }

        // ---- QK^T swapped, C-init = -m_run: sacc[n][j] = S[kv][q=fr] - m_run
        fx4 sacc[4];
        #pragma unroll
        for (int n = 0; n < 4; n++) sacc[n] = (fx4)(-m_run);
        __builtin_amdgcn_s_setprio(1);
        #pragma unroll
        for (int s = 0; s < 2; s++)
            #pragma unroll
            for (int n = 0; n < 4; n++) {
                bfx8 kF = *(const bfx8*)&sK[buf][(n * 16 + fr) * 64 + (((s * 4 + fq) ^ (fr & 7)) * 8)];
                sacc[n] = __builtin_amdgcn_mfma_f32_16x16x32_bf16(kF, qF[s], sacc[n], 0, 0, 0);
            }
        __builtin_amdgcn_s_setprio(0);

        // ---- per-lane max of this lane's 16 scores; cross-lane reduce only if rescale
        float t0 = fmaxf(fmaxf(sacc[0][0], sacc[0][1]), sacc[0][2]);
        float t1 = fmaxf(fmaxf(sacc[0][3], sacc[1][0]), sacc[1][1]);
        float t2 = fmaxf(fmaxf(sacc[1][2], sacc[1][3]), sacc[2][0]);
        float t3 = fmaxf(fmaxf(sacc[2][1], sacc[2][2]), sacc[2][3]);
        float t4 = fmaxf(fmaxf(sacc[3][0], sacc[3][1]), sacc[3][2]);
        float smax = fmaxf(fmaxf(fmaxf(t0, t1), t2), fmaxf(fmaxf(t3, t4), sacc[3][3]));
        if (!__all(smax <= 8.0f)) {            // defer-max: P bounded by 2^8
            smax = fmaxf(smax, __shfl_xor(smax, 16));
            smax = fmaxf(smax, __shfl_xor(smax, 32));
            float delta = fmaxf(smax, 0.0f);   // per-q-row, uniform across fq
            float scal = __builtin_amdgcn_exp2f(-delta);
            m_run += delta;
            #pragma unroll
            for (int n = 0; n < 4; n++)
                #pragma unroll
                for (int j = 0; j < 4; j++) sacc[n][j] -= delta;
            #pragma unroll
            for (int db = 0; db < 4; db++) oacc[db] *= scal;
            oextra *= scal;
        }
        float p[4][4];
        #pragma unroll
        for (int n = 0; n < 4; n++)
            #pragma unroll
            for (int j = 0; j < 4; j++)
                p[n][j] = __builtin_amdgcn_exp2f(sacc[n][j]);

        // ---- pack P to bf16 pairs; V-permutation makes this the exact B-operand
        unsigned int u[4][2];
        #pragma unroll
        for (int n = 0; n < 4; n++)
            #pragma unroll
            for (int h = 0; h < 2; h++)
                u[n][h] = cvtpk_bf16(p[n][2 * h], p[n][2 * h + 1]);

        // ---- PV swapped + ones-row (l): oacc[db] = O^T[d][q=fr], oextra = l[q=fr]
        __builtin_amdgcn_s_setprio(1);
        #pragma unroll
        for (int s = 0; s < 2; s++) {
            union { unsigned int ui[4]; bfx8 bf; } cv;
            cv.ui[0] = u[2 * s][0];     cv.ui[1] = u[2 * s][1];
            cv.ui[2] = u[2 * s + 1][0]; cv.ui[3] = u[2 * s + 1][1];
            #pragma unroll
            for (int db = 0; db < 4; db++) {
                bfx8 vF = *(const bfx8*)&sVt[buf][(db * 16 + fr) * 64 + (((s * 4 + fq) ^ (fr & 7)) * 8)];
                oacc[db] = __builtin_amdgcn_mfma_f32_16x16x32_bf16(vF, cv.bf, oacc[db], 0, 0, 0);
            }
            oextra = __builtin_amdgcn_mfma_f32_16x16x32_bf16(ones_u.bf, cv.bf, oextra, 0, 0, 0);
        }
        __builtin_amdgcn_s_setprio(0);
    }

    // ---- epilogue: O^T in regs -> ao row-major (all oextra[j] rows identical)
    float invl = 1.0f / oextra[0];
    const int qrow = qt * 64 + wave * 16 + fr;
    unsigned short* aop = ao + (size_t)(b * TLEN + qrow) * 1024 + hh * 64 + fq * 4;
    #pragma unroll
    for (int db = 0; db < 4; db++) {
        usx4 o4;
        #pragma unroll
        for (int j = 0; j < 4; j++) o4[j] = f2bf(oacc[db][j] * invl);
        *(usx4*)(aop + db * 16) = o4;
    }
}

extern "C" void kernel_launch(void* const* d_in, const int* in_sizes, int n_in,
                              void* d_out, int out_size, void* d_ws, size_t ws_size,
                              hipStream_t stream) {
    const float* x    = (const float*)d_in[0];
    const float* wq   = (const float*)d_in[1];
    const float* wk   = (const float*)d_in[2];
    const float* wv   = (const float*)d_in[3];
    const float* wo   = (const float*)d_in[4];
    const float* lng  = (const float*)d_in[5];
    const float* lnb  = (const float*)d_in[6];

    char* ws = (char*)d_ws;
    unsigned short* wob  = (unsigned short*)(ws);                // 2 MB  [1024][1024] bf16
    unsigned short* wqkv = (unsigned short*)(ws + (2u  << 20));  // 6 MB  [3072][1024] bf16 (wq|wk|wv)
    unsigned short* hbuf = (unsigned short*)(ws + (8u  << 20));  // 8 MB  [4096][1024] bf16
    unsigned short* qk   = (unsigned short*)(ws + (16u << 20));  // 16 MB [4096][2048] bf16 (q|k, roped)
    unsigned short* vtb  = (unsigned short*)(ws + (32u << 20));  // 8 MB  [32 bh][64 d][2048 t'] (permuted)
    unsigned short* ao   = (unsigned short*)(ws + (8u  << 20));  // aliases hbuf (dead after qkvt)

    ln_kernel<<<ROWS, 256, 0, stream>>>(x, lng, lnb, hbuf);
    wconv_kernel<<<1024, 256, 0, stream>>>(wq, wk, wv, wo, wqkv, wob);
    qkvt_gemm<<<768, 256, 0, stream>>>(hbuf, wqkv, qk, vtb);
    attn_kernel<<<dim3(32, 32), 256, 0, stream>>>(qk, vtb, ao);
    gemm_out64<<<dim3(32, 16), 256, 0, stream>>>(ao, wob, (float*)d_out);
}

// Round 9
// 127.425 us; speedup vs baseline: 1.3801x; 1.0505x over previous
//
#include <hip/hip_runtime.h>
#include <hip/hip_bf16.h>

typedef __attribute__((ext_vector_type(4))) float          fx4;
typedef __attribute__((ext_vector_type(8))) __bf16         bfx8;
typedef __attribute__((ext_vector_type(8))) unsigned short usx8;
typedef __attribute__((ext_vector_type(4))) unsigned short usx4;

#define TLEN 2048
#define ROWS 4096   /* B*T */
#define D    1024

__device__ __forceinline__ float bf2f(unsigned short u) {
    union { unsigned int i; float f; } v; v.i = ((unsigned int)u) << 16; return v.f;
}
__device__ __forceinline__ unsigned short f2bf(float f) {
    union { float f; unsigned int i; } v; v.f = f;
    unsigned int r = v.i + 0x7fffu + ((v.i >> 16) & 1u);
    return (unsigned short)(r >> 16);
}
__device__ __forceinline__ unsigned int cvtpk_bf16(float lo, float hi) {
    unsigned int r;
    asm("v_cvt_pk_bf16_f32 %0, %1, %2" : "=v"(r) : "v"(lo), "v"(hi));
    return r;
}
__device__ __forceinline__ float fast_cos(float a) {
    float r; asm("v_cos_f32 %0, %1" : "=v"(r) : "v"(a)); return r;
}
__device__ __forceinline__ float fast_sin(float a) {
    float r; asm("v_sin_f32 %0, %1" : "=v"(r) : "v"(a)); return r;
}
__device__ __forceinline__ void gload_lds16(const unsigned short* g, unsigned short* l) {
    __builtin_amdgcn_global_load_lds((const __attribute__((address_space(1))) void*)g,
                                     (__attribute__((address_space(3))) void*)l, 16, 0, 0);
}

// ---------------- Prep: LN (blocks 0..4095) + weight convert (blocks 4096..5119) ----------------
__device__ __forceinline__ usx4 cvt4(fx4 a) {
    usx4 o;
    #pragma unroll
    for (int j = 0; j < 4; j++) o[j] = f2bf(a[j]);
    return o;
}
__global__ __launch_bounds__(256) void prep_kernel(const float* __restrict__ x,
                                                   const float* __restrict__ g,
                                                   const float* __restrict__ bta,
                                                   const float* __restrict__ wq, const float* __restrict__ wk,
                                                   const float* __restrict__ wv, const float* __restrict__ wo,
                                                   unsigned short* __restrict__ hout,
                                                   unsigned short* __restrict__ wqkv,
                                                   unsigned short* __restrict__ wob) {
    const int tid = threadIdx.x;
    if (blockIdx.x >= 4096) {
        const int i = (blockIdx.x - 4096) * 256 + tid;   // usx4 units, 262144 per matrix
        ((usx4*)wqkv)[i]          = cvt4(((const fx4*)wq)[i]);
        ((usx4*)wqkv)[262144 + i] = cvt4(((const fx4*)wk)[i]);
        ((usx4*)wqkv)[524288 + i] = cvt4(((const fx4*)wv)[i]);
        ((usx4*)wob)[i]           = cvt4(((const fx4*)wo)[i]);
        return;
    }
    const int row = blockIdx.x;
    fx4 v = ((const fx4*)(x + (size_t)row * D))[tid];
    float s  = v[0] + v[1] + v[2] + v[3];
    float s2 = v[0]*v[0] + v[1]*v[1] + v[2]*v[2] + v[3]*v[3];
    #pragma unroll
    for (int mk = 32; mk >= 1; mk >>= 1) { s += __shfl_xor(s, mk); s2 += __shfl_xor(s2, mk); }
    __shared__ float red[8];
    const int wave = tid >> 6, lane = tid & 63;
    if (lane == 0) { red[wave] = s; red[4 + wave] = s2; }
    __syncthreads();
    s  = red[0] + red[1] + red[2] + red[3];
    s2 = red[4] + red[5] + red[6] + red[7];
    float mu   = s * (1.0f / D);
    float var  = s2 * (1.0f / D) - mu * mu;
    float rstd = rsqrtf(var + 1e-5f);
    fx4 gv = ((const fx4*)g)[tid];
    fx4 bv = ((const fx4*)bta)[tid];
    usx4 o;
    #pragma unroll
    for (int j = 0; j < 4; j++) o[j] = f2bf((v[j] - mu) * rstd * gv[j] + bv[j]);
    ((usx4*)hout)[(size_t)row * 256 + tid] = o;
}

// ---------------- Merged QK + V^T GEMM (768 blocks -> 3/CU) ----------------
// Blocks 0..511: C[tok][2048 qk] = hbuf * wqk^T with FUSED RoPE (+ QS on q), bf16.
// Blocks 512..767: Vt — C[d][tok] = wv * hbuf^T stored to Vt[(b*16+d>>6)*64+(d&63)][t']
//   with within-64-token permutation (kills attn's P cross-lane movement).
__global__ __launch_bounds__(256) void qkvt_gemm(const unsigned short* __restrict__ hbuf,
                                                 const unsigned short* __restrict__ wqkv,
                                                 unsigned short* __restrict__ qkout,
                                                 unsigned short* __restrict__ vtout) {
    constexpr int K = 1024;
    __shared__ __align__(16) unsigned short As[128 * 32];
    __shared__ __align__(16) unsigned short Bs[128 * 32];
    const int tid = threadIdx.x, lane = tid & 63, wave = tid >> 6;
    const int fr = lane & 15, fq = lane >> 4;
    const int wr = wave >> 1, wc = wave & 1;

    const int id = blockIdx.x;
    const bool isqk = id < 512;
    int bm, bn;
    const unsigned short *Ab, *Bb;
    if (isqk) {
        bm = id & 31; bn = id >> 5;                                   // 32 x 16
        Ab = hbuf + (size_t)(bm * 128) * K;
        Bb = wqkv + (size_t)(bn * 128) * K;
    } else {
        int j = id - 512; bm = j & 7; bn = j >> 3;                    // 8 x 32
        Ab = wqkv + (size_t)(2048 * 1024) + (size_t)(bm * 128) * K;   // wv
        Bb = hbuf + (size_t)(bn * 128) * K;
    }

    const int str0 = wave * 32 + (lane >> 2);
    const int stc  = (lane & 3) * 8;

    fx4 acc[4][4];
    #pragma unroll
    for (int m = 0; m < 4; m++)
        #pragma unroll
        for (int n = 0; n < 4; n++) acc[m][n] = (fx4)0.0f;

    for (int kt = 0; kt < K; kt += 32) {
        gload_lds16(Ab + (size_t)str0 * K + kt + stc,        &As[str0 * 32 + stc]);
        gload_lds16(Ab + (size_t)(str0 + 16) * K + kt + stc, &As[(str0 + 16) * 32 + stc]);
        gload_lds16(Bb + (size_t)str0 * K + kt + stc,        &Bs[str0 * 32 + stc]);
        gload_lds16(Bb + (size_t)(str0 + 16) * K + kt + stc, &Bs[(str0 + 16) * 32 + stc]);
        __syncthreads();
        bfx8 aF[4], bF[4];
        #pragma unroll
        for (int m = 0; m < 4; m++) aF[m] = *(const bfx8*)&As[(wr * 64 + m * 16 + fr) * 32 + fq * 8];
        #pragma unroll
        for (int n = 0; n < 4; n++) bF[n] = *(const bfx8*)&Bs[(wc * 64 + n * 16 + fr) * 32 + fq * 8];
        #pragma unroll
        for (int m = 0; m < 4; m++)
            #pragma unroll
            for (int n = 0; n < 4; n++)
                acc[m][n] = __builtin_amdgcn_mfma_f32_16x16x32_bf16(aF[m], bF[n], acc[m][n], 0, 0, 0);
        __syncthreads();
    }

    const int row0 = bm * 128 + wr * 64 + fq * 4;
    const int col0 = bn * 128 + wc * 64 + fr;
    if (isqk) {
        const float QS = 0.125f * 1.44269504088896f;
        const bool isq = bn < 8;
        const float sgn = (fr & 1) ? 1.0f : -1.0f;
        float fp[4];
        #pragma unroll
        for (int n = 0; n < 4; n++) {
            float pif = (float)(n * 8 + (fr >> 1));
            fp[n] = __builtin_amdgcn_exp2f(fmaf(pif, -0.415241011861f, -2.651496129472f));
        }
        #pragma unroll
        for (int m = 0; m < 4; m++) {
            const int rbase = row0 + m * 16;
            const float tf = (float)(rbase & (TLEN - 1));
            #pragma unroll
            for (int n = 0; n < 4; n++) {
                #pragma unroll
                for (int j = 0; j < 4; j++) {
                    float a = __builtin_amdgcn_fractf((tf + (float)j) * fp[n]);
                    float c = fast_cos(a), s = fast_sin(a);
                    float self = acc[m][n][j];
                    float other = __shfl_xor(self, 1);
                    float o = self * c + other * (sgn * s);
                    if (isq) o *= QS;
                    qkout[(size_t)(rbase + j) * 2048 + col0 + n * 16] = f2bf(o);
                }
            }
        }
    } else {
        const int bb = bn >> 4;
        // permuted within-64 column: t_w = n*16+fr  ->  (n>>1)*32+(fr>>2)*8+(n&1)*4+(fr&3)
        #pragma unroll
        for (int m = 0; m < 4; m++)
            #pragma unroll
            for (int n = 0; n < 4; n++) {
                const int t = (col0 + n * 16) & (TLEN - 1);
                const int tp = (t & ~63) | ((n >> 1) * 32 + ((fr >> 2)) * 8 + ((n & 1)) * 4 + (fr & 3));
                #pragma unroll
                for (int j = 0; j < 4; j++) {
                    const int d = row0 + m * 16 + j;
                    vtout[(((size_t)(bb * 16 + (d >> 6)) * 64) + (d & 63)) * TLEN + tp] = f2bf(acc[m][n][j]);
                }
            }
    }
}

// ---------------- Output GEMM: 128x64 tile, 512 blocks, f32 out ----------------
__global__ __launch_bounds__(256) void gemm_out64(const unsigned short* __restrict__ A,
                                                  const unsigned short* __restrict__ B,
                                                  float* __restrict__ C) {
    constexpr int K = 1024;
    __shared__ __align__(16) unsigned short As[128 * 32];
    __shared__ __align__(16) unsigned short Bs[64 * 32];
    const int tid = threadIdx.x, lane = tid & 63, wave = tid >> 6;
    const int fr = lane & 15, fq = lane >> 4;
    const int bm = blockIdx.x, bn = blockIdx.y;
    const int wr = wave >> 1, wc = wave & 1;

    const int strA = wave * 32 + (lane >> 2);
    const int strB = wave * 16 + (lane >> 2);
    const int stc  = (lane & 3) * 8;
    const unsigned short* Ab = A + (size_t)(bm * 128) * K;
    const unsigned short* Bb = B + (size_t)(bn * 64) * K;

    fx4 acc[4][2];
    #pragma unroll
    for (int m = 0; m < 4; m++)
        #pragma unroll
        for (int n = 0; n < 2; n++) acc[m][n] = (fx4)0.0f;

    for (int kt = 0; kt < K; kt += 32) {
        gload_lds16(Ab + (size_t)strA * K + kt + stc,        &As[strA * 32 + stc]);
        gload_lds16(Ab + (size_t)(strA + 16) * K + kt + stc, &As[(strA + 16) * 32 + stc]);
        gload_lds16(Bb + (size_t)strB * K + kt + stc,        &Bs[strB * 32 + stc]);
        __syncthreads();
        bfx8 aF[4], bF[2];
        #pragma unroll
        for (int m = 0; m < 4; m++) aF[m] = *(const bfx8*)&As[(wr * 64 + m * 16 + fr) * 32 + fq * 8];
        #pragma unroll
        for (int n = 0; n < 2; n++) bF[n] = *(const bfx8*)&Bs[(wc * 32 + n * 16 + fr) * 32 + fq * 8];
        #pragma unroll
        for (int m = 0; m < 4; m++)
            #pragma unroll
            for (int n = 0; n < 2; n++)
                acc[m][n] = __builtin_amdgcn_mfma_f32_16x16x32_bf16(aF[m], bF[n], acc[m][n], 0, 0, 0);
        __syncthreads();
    }

    const int row0 = bm * 128 + wr * 64 + fq * 4;
    const int col0 = bn * 64 + wc * 32 + fr;
    #pragma unroll
    for (int m = 0; m < 4; m++)
        #pragma unroll
        for (int n = 0; n < 2; n++)
            #pragma unroll
            for (int j = 0; j < 4; j++)
                C[(size_t)(row0 + m * 16 + j) * 1024 + col0 + n * 16] = acc[m][n][j];
}

// ---------------- Flash attention (full, non-causal), bf16 MFMA ----------------
// 4 waves; wave owns 32 q-rows (two 16-row groups g0,g1); block owns 128 q.
// K/V LDS fragments are q-invariant: read once, feed both groups' MFMAs.
// softmax(g1) overlaps PV(g0) on VALU/TRANS vs MFMA pipes. Swapped QK^T with
// C-init = -m_run, defer-max, l via ones-row MFMA, V pre-permuted (no P shuffle).
__global__ __launch_bounds__(256) void attn_kernel(const unsigned short* __restrict__ qk,
                                                   const unsigned short* __restrict__ vt,
                                                   unsigned short* __restrict__ ao) {
    // XCD swizzle: 512 blocks -> each XCD hosts 4 consecutive bh groups
    const int flat = blockIdx.x + (blockIdx.y << 4);
    const int sid  = (flat & 7) * 64 + (flat >> 3);
    const int qt = sid & 15, bh = sid >> 4;
    const int b = bh >> 4, hh = bh & 15;
    const int tid = threadIdx.x, lane = tid & 63, wave = tid >> 6;
    const int fr = lane & 15, fq = lane >> 4;

    __shared__ __align__(16) unsigned short sK[2][64 * 64];   // swizzled K tile
    __shared__ __align__(16) unsigned short sVt[2][64 * 64];  // swizzled V^T tile

    const size_t rs = 2048;
    const unsigned short* qb  = qk + (size_t)b * TLEN * rs + hh * 64;
    const unsigned short* kb  = qb + 1024;
    const unsigned short* vtb = vt + (size_t)bh * (64 * TLEN);

    bfx8 qF[2][2];
    #pragma unroll
    for (int g = 0; g < 2; g++) {
        int qrow = qt * 128 + g * 64 + wave * 16 + fr;
        const unsigned short* qp = qb + (size_t)qrow * rs + fq * 8;
        qF[g][0] = *(const bfx8*)qp;
        qF[g][1] = *(const bfx8*)(qp + 32);
    }
    union { unsigned short us[8]; bfx8 bf; } ones_u;
    #pragma unroll
    for (int i = 0; i < 8; i++) ones_u.us[i] = 0x3F80;   // bf16 1.0

    const int srow = lane >> 3;
    const int scol = ((lane & 7) ^ srow) * 8;

    // ---- prologue: stage tile 0 into buf 0
    #pragma unroll
    for (int i = 0; i < 2; i++) {
        int rg = wave * 2 + i;
        gload_lds16(kb  + (size_t)(rg * 8 + srow) * rs + scol,   &sK[0][rg * 512 + lane * 8]);
        gload_lds16(vtb + (size_t)(rg * 8 + srow) * TLEN + scol, &sVt[0][rg * 512 + lane * 8]);
    }

    float m_run[2] = {0.0f, 0.0f};
    fx4 oacc[2][4];
    fx4 oextra[2] = {(fx4)0.0f, (fx4)0.0f};
    #pragma unroll
    for (int g = 0; g < 2; g++)
        #pragma unroll
        for (int db = 0; db < 4; db++) oacc[g][db] = (fx4)0.0f;

    #pragma unroll 2
    for (int t = 0; t < 32; ++t) {
        const int buf = t & 1;
        __syncthreads();   // staging of buf drained; prior reads of buf^1 done

        // ---- prefetch next tile into buf^1 (async, drains at next barrier)
        if (t + 1 < 32) {
            const int kt = (t + 1) * 64;
            #pragma unroll
            for (int i = 0; i < 2; i++) {
                int rg = wave * 2 + i;
                gload_lds16(kb  + (size_t)(kt + rg * 8 + srow) * rs + scol,
                            &sK[buf ^ 1][rg * 512 + lane * 8]);
                gload_lds16(vtb + (size_t)(rg * 8 + srow) * TLEN + kt + scol,
                            &sVt[buf ^ 1][rg * 512 + lane * 8]);
            }
        }

        // ---- K fragments once (q-invariant), then QK^T for both groups
        bfx8 kF[2][4];
        #pragma unroll
        for (int s = 0; s < 2; s++)
            #pragma unroll
            for (int n = 0; n < 4; n++)
                kF[s][n] = *(const bfx8*)&sK[buf][(n * 16 + fr) * 64 + (((s * 4 + fq) ^ (fr & 7)) * 8)];
        fx4 sacc0[4], sacc1[4];
        #pragma unroll
        for (int n = 0; n < 4; n++) { sacc0[n] = (fx4)(-m_run[0]); sacc1[n] = (fx4)(-m_run[1]); }
        __builtin_amdgcn_s_setprio(1);
        #pragma unroll
        for (int s = 0; s < 2; s++)
            #pragma unroll
            for (int n = 0; n < 4; n++)
                sacc0[n] = __builtin_amdgcn_mfma_f32_16x16x32_bf16(kF[s][n], qF[0][s], sacc0[n], 0, 0, 0);
        #pragma unroll
        for (int s = 0; s < 2; s++)
            #pragma unroll
            for (int n = 0; n < 4; n++)
                sacc1[n] = __builtin_amdgcn_mfma_f32_16x16x32_bf16(kF[s][n], qF[1][s], sacc1[n], 0, 0, 0);
        __builtin_amdgcn_s_setprio(0);

        // ---- softmax g0
        unsigned int u0[4][2];
        {
            float t0 = fmaxf(fmaxf(sacc0[0][0], sacc0[0][1]), sacc0[0][2]);
            float t1 = fmaxf(fmaxf(sacc0[0][3], sacc0[1][0]), sacc0[1][1]);
            float t2 = fmaxf(fmaxf(sacc0[1][2], sacc0[1][3]), sacc0[2][0]);
            float t3 = fmaxf(fmaxf(sacc0[2][1], sacc0[2][2]), sacc0[2][3]);
            float t4 = fmaxf(fmaxf(sacc0[3][0], sacc0[3][1]), sacc0[3][2]);
            float smax = fmaxf(fmaxf(fmaxf(t0, t1), t2), fmaxf(fmaxf(t3, t4), sacc0[3][3]));
            if (!__all(smax <= 8.0f)) {
                smax = fmaxf(smax, __shfl_xor(smax, 16));
                smax = fmaxf(smax, __shfl_xor(smax, 32));
                float delta = fmaxf(smax, 0.0f);
                float scal = __builtin_amdgcn_exp2f(-delta);
                m_run[0] += delta;
                #pragma unroll
                for (int n = 0; n < 4; n++)
                    #pragma unroll
                    for (int j = 0; j < 4; j++) sacc0[n][j] -= delta;
                #pragma unroll
                for (int db = 0; db < 4; db++) oacc[0][db] *= scal;
                oextra[0] *= scal;
            }
            #pragma unroll
            for (int n = 0; n < 4; n++) {
                float plo0 = __builtin_amdgcn_exp2f(sacc0[n][0]);
                float phi0 = __builtin_amdgcn_exp2f(sacc0[n][1]);
                float plo1 = __builtin_amdgcn_exp2f(sacc0[n][2]);
                float phi1 = __builtin_amdgcn_exp2f(sacc0[n][3]);
                u0[n][0] = cvtpk_bf16(plo0, phi0);
                u0[n][1] = cvtpk_bf16(plo1, phi1);
            }
        }

        // ---- V fragments once (q-invariant)
        bfx8 vF[2][4];
        #pragma unroll
        for (int s = 0; s < 2; s++)
            #pragma unroll
            for (int db = 0; db < 4; db++)
                vF[s][db] = *(const bfx8*)&sVt[buf][(db * 16 + fr) * 64 + (((s * 4 + fq) ^ (fr & 7)) * 8)];

        // ---- PV g0 (MFMA) — softmax g1 below overlaps on VALU/TRANS
        __builtin_amdgcn_s_setprio(1);
        #pragma unroll
        for (int s = 0; s < 2; s++) {
            union { unsigned int ui[4]; bfx8 bf; } cv;
            cv.ui[0] = u0[2 * s][0];     cv.ui[1] = u0[2 * s][1];
            cv.ui[2] = u0[2 * s + 1][0]; cv.ui[3] = u0[2 * s + 1][1];
            #pragma unroll
            for (int db = 0; db < 4; db++)
                oacc[0][db] = __builtin_amdgcn_mfma_f32_16x16x32_bf16(vF[s][db], cv.bf, oacc[0][db], 0, 0, 0);
            oextra[0] = __builtin_amdgcn_mfma_f32_16x16x32_bf16(ones_u.bf, cv.bf, oextra[0], 0, 0, 0);
        }
        __builtin_amdgcn_s_setprio(0);

        // ---- softmax g1
        unsigned int u1[4][2];
        {
            float t0 = fmaxf(fmaxf(sacc1[0][0], sacc1[0][1]), sacc1[0][2]);
            float t1 = fmaxf(fmaxf(sacc1[0][3], sacc1[1][0]), sacc1[1][1]);
            float t2 = fmaxf(fmaxf(sacc1[1][2], sacc1[1][3]), sacc1[2][0]);
            float t3 = fmaxf(fmaxf(sacc1[2][1], sacc1[2][2]), sacc1[2][3]);
            float t4 = fmaxf(fmaxf(sacc1[3][0], sacc1[3][1]), sacc1[3][2]);
            float smax = fmaxf(fmaxf(fmaxf(t0, t1), t2), fmaxf(fmaxf(t3, t4), sacc1[3][3]));
            if (!__all(smax <= 8.0f)) {
                smax = fmaxf(smax, __shfl_xor(smax, 16));
                smax = fmaxf(smax, __shfl_xor(smax, 32));
                float delta = fmaxf(smax, 0.0f);
                float scal = __builtin_amdgcn_exp2f(-delta);
                m_run[1] += delta;
                #pragma unroll
                for (int n = 0; n < 4; n++)
                    #pragma unroll
                    for (int j = 0; j < 4; j++) sacc1[n][j] -= delta;
                #pragma unroll
                for (int db = 0; db < 4; db++) oacc[1][db] *= scal;
                oextra[1] *= scal;
            }
            #pragma unroll
            for (int n = 0; n < 4; n++) {
                float plo0 = __builtin_amdgcn_exp2f(sacc1[n][0]);
                float phi0 = __builtin_amdgcn_exp2f(sacc1[n][1]);
                float plo1 = __builtin_amdgcn_exp2f(sacc1[n][2]);
                float phi1 = __builtin_amdgcn_exp2f(sacc1[n][3]);
                u1[n][0] = cvtpk_bf16(plo0, phi0);
                u1[n][1] = cvtpk_bf16(plo1, phi1);
            }
        }

        // ---- PV g1
        __builtin_amdgcn_s_setprio(1);
        #pragma unroll
        for (int s = 0; s < 2; s++) {
            union { unsigned int ui[4]; bfx8 bf; } cv;
            cv.ui[0] = u1[2 * s][0];     cv.ui[1] = u1[2 * s][1];
            cv.ui[2] = u1[2 * s + 1][0]; cv.ui[3] = u1[2 * s + 1][1];
            #pragma unroll
            for (int db = 0; db < 4; db++)
                oacc[1][db] = __builtin_amdgcn_mfma_f32_16x16x32_bf16(vF[s][db], cv.bf, oacc[1][db], 0, 0, 0);
            oextra[1] = __builtin_amdgcn_mfma_f32_16x16x32_bf16(ones_u.bf, cv.bf, oextra[1], 0, 0, 0);
        }
        __builtin_amdgcn_s_setprio(0);
    }

    // ---- epilogue
    #pragma unroll
    for (int g = 0; g < 2; g++) {
        float invl = 1.0f / oextra[g][0];
        const int qrow = qt * 128 + g * 64 + wave * 16 + fr;
        unsigned short* aop = ao + (size_t)(b * TLEN + qrow) * 1024 + hh * 64 + fq * 4;
        #pragma unroll
        for (int db = 0; db < 4; db++) {
            usx4 o4;
            #pragma unroll
            for (int j = 0; j < 4; j++) o4[j] = f2bf(oacc[g][db][j] * invl);
            *(usx4*)(aop + db * 16) = o4;
        }
    }
}

extern "C" void kernel_launch(void* const* d_in, const int* in_sizes, int n_in,
                              void* d_out, int out_size, void* d_ws, size_t ws_size,
                              hipStream_t stream) {
    const float* x    = (const float*)d_in[0];
    const float* wq   = (const float*)d_in[1];
    const float* wk   = (const float*)d_in[2];
    const float* wv   = (const float*)d_in[3];
    const float* wo   = (const float*)d_in[4];
    const float* lng  = (const float*)d_in[5];
    const float* lnb  = (const float*)d_in[6];

    char* ws = (char*)d_ws;
    unsigned short* wob  = (unsigned short*)(ws);                // 2 MB  [1024][1024] bf16
    unsigned short* wqkv = (unsigned short*)(ws + (2u  << 20));  // 6 MB  [3072][1024] bf16 (wq|wk|wv)
    unsigned short* hbuf = (unsigned short*)(ws + (8u  << 20));  // 8 MB  [4096][1024] bf16
    unsigned short* qk   = (unsigned short*)(ws + (16u << 20));  // 16 MB [4096][2048] bf16 (q|k, roped)
    unsigned short* vtb  = (unsigned short*)(ws + (32u << 20));  // 8 MB  [32 bh][64 d][2048 t'] (permuted)
    unsigned short* ao   = (unsigned short*)(ws + (8u  << 20));  // aliases hbuf (dead after qkvt)

    prep_kernel<<<5120, 256, 0, stream>>>(x, lng, lnb, wq, wk, wv, wo, hbuf, wqkv, wob);
    qkvt_gemm<<<768, 256, 0, stream>>>(hbuf, wqkv, qk, vtb);
    attn_kernel<<<dim3(16, 32), 256, 0, stream>>>(qk, vtb, ao);
    gemm_out64<<<dim3(32, 16), 256, 0, stream>>>(ao, wob, (float*)d_out);
}